// Round 15
// baseline (916.595 us; speedup 1.0000x reference)
//
#include <hip/hip_runtime.h>
#include <hip/hip_bf16.h>
#include <cstdint>
#include <cstddef>

// B=16, S=128, IN=200, H=256, 4H=1024, 2H=512

typedef __attribute__((ext_vector_type(8))) short bf16x8;
typedef __attribute__((ext_vector_type(4))) float f32x4;
typedef __attribute__((ext_vector_type(4))) unsigned short u16x4;

__device__ __forceinline__ float bf2f(unsigned short u) {
    return __uint_as_float(((unsigned)u) << 16);
}
__device__ __forceinline__ unsigned short f2bf(float f) {
    unsigned u = __float_as_uint(f);
    u = (u + 0x7FFFu + ((u >> 16) & 1u)) >> 16;
    return (unsigned short)u;
}

// float -> OCP e4m3fn with RNE (software; used in prep only)
__device__ __forceinline__ unsigned f2e4m3(float f) {
    unsigned u = __float_as_uint(f);
    unsigned s = (u >> 24) & 0x80u;
    int expf_ = (int)((u >> 23) & 0xFF);
    if (expf_ == 0) return s;
    int exp = expf_ - 127;
    if (exp < -10) return s;
    unsigned M = (u & 0x7FFFFF) | 0x800000;
    int e8 = exp + 7;
    int shift = 20;
    if (e8 < 1) { shift = 21 - e8; e8 = 0; }
    unsigned q = M >> shift;
    unsigned rem = M & ((1u << shift) - 1u);
    unsigned half = 1u << (shift - 1);
    if (rem > half || (rem == half && (q & 1))) q++;
    if (q >= 16) { q >>= 1; e8++; }
    if (e8 == 0 && (q & 8)) e8 = 1;
    if (e8 >= 16 || (e8 == 15 && (q & 7) == 7)) return s | 0x7Eu;
    return s | ((unsigned)e8 << 4) | (q & 7u);
}

// ---------------- prep kernels ----------------

__global__ void k_transpose_N1024(const float* __restrict__ src, float* __restrict__ dst, int K) {
    int z = blockIdx.z;
    int idx = blockIdx.x * 256 + threadIdx.x;
    if (idx >= K * 1024) return;
    int k = idx >> 10, n = idx & 1023;
    dst[(size_t)z * K * 1024 + idx] = src[(size_t)z * 1024 * K + (size_t)n * K + k];
}

// Whh -> fp8 A-fragments of 64*Whh, k-perm cOf(e)=(e&1)*4+(e>>1).
// Layout: Wfrag8[((((d*16+w)*8+ks)*4+t4)*64+l)*8 + e]  (conflict-free stride-8)
__global__ void k_wfrag8(const float* __restrict__ Whh, unsigned char* __restrict__ Wfrag8) {
    int idx = blockIdx.x * 256 + threadIdx.x;   // 65536 total
    int l = idx & 63;
    int t = (idx >> 6) & 3;
    int ks = (idx >> 8) & 7;
    int w = (idx >> 11) & 15;
    int d = idx >> 15;
    int r = l & 15;
    int kbase = ks * 32 + (l >> 4) * 8;
    int row = (r & 3) * 256 + w * 16 + t * 4 + (r >> 2);
    const float* src = Whh + (size_t)d * (1024 * 256) + (size_t)row * 256 + kbase;
    unsigned char* dst = Wfrag8 + (size_t)idx * 8;
#pragma unroll
    for (int e = 0; e < 8; ++e) {
        int c = (e & 1) * 4 + (e >> 1);
        dst[e] = (unsigned char)f2e4m3(64.f * src[c]);
    }
}

__global__ void k_w2frag(const float* __restrict__ W2, unsigned short* __restrict__ w2f) {
    int idx = blockIdx.x * 256 + threadIdx.x;   // 4096 total
    if (idx >= 4096) return;
    int l = idx & 63;
    int ks = (idx >> 6) & 7;
    int nt = idx >> 9;
    const float* src = W2 + (size_t)(nt * 16 + (l & 15)) * 256 + ks * 32 + (l >> 4) * 8;
    unsigned short* dst = w2f + (size_t)idx * 8;
#pragma unroll
    for (int e = 0; e < 8; ++e) dst[e] = f2bf(src[e]);
}

__global__ void k_w1t(const float* __restrict__ W1, float* __restrict__ dst) {
    int idx = blockIdx.x * 256 + threadIdx.x;
    if (idx >= 512 * 512) return;
    int k = idx >> 9, o = idx & 511;
    dst[idx] = (o < 256) ? W1[(size_t)o * 1024 + k] : W1[(size_t)(o - 256) * 1024 + 512 + k];
}

__global__ void k_bias(const float* __restrict__ bih0, const float* __restrict__ bhh0,
                       const float* __restrict__ bih1, const float* __restrict__ bhh1,
                       const float* __restrict__ b1,
                       float* __restrict__ bsum0, float* __restrict__ bsum1, float* __restrict__ bhab) {
    int idx = blockIdx.x * 256 + threadIdx.x;
    if (idx < 2048) bsum0[idx] = bih0[idx] + bhh0[idx];
    else if (idx < 4096) { int i = idx - 2048; bsum1[i] = bih1[i] + bhh1[i]; }
    else if (idx < 4608) { int i = idx - 4096; bhab[i] = (i < 256) ? b1[i] : 0.f; }
}

// xg -> xgfrag, PRE-SCALED by 64
__global__ __launch_bounds__(256) void k_reorder(const float* __restrict__ xg, float* __restrict__ xgf) {
    int idx = blockIdx.x * 256 + threadIdx.x;   // 1048576 total
    int n4 = idx & 255;
    int m = (idx >> 8) & 2047;
    int d = idx >> 19;
    int n0 = n4 * 4;
    int q = n0 >> 8;
    int jbase = n0 & 255;
    int b = m >> 7, t = m & 127;
    float4 v = *(const float4*)(xg + ((size_t)(d * 2048 + m)) * 1024 + n0);
    float* base = xgf + (size_t)d * 2097152;
    float vv[4] = {v.x * 64.f, v.y * 64.f, v.z * 64.f, v.w * 64.f};
#pragma unroll
    for (int dj = 0; dj < 4; ++dj) {
        int j = jbase + dj;
        int fi = (t * 4096 + (j >> 4) * 256 + ((j >> 2) & 3) * 64 + dj * 16 + b) * 4 + q;
        base[fi] = vv[dj];
    }
}

// ---------------- generic GEMM ----------------
__global__ __launch_bounds__(256) void k_gemm(
    const float* __restrict__ A, const float* __restrict__ Wt,
    const float* __restrict__ bias, float* __restrict__ out,
    int M, int K, int N)
{
    int z = blockIdx.z;
    const float* Wtz = Wt + (size_t)z * K * N;
    float* outz = out + (size_t)z * M * N;
    const float* biasz = bias + (size_t)z * N;

    __shared__ float As[16 * 512];
    int tid = threadIdx.x;
    int mq = tid >> 6;
    int nq = tid & 63;
    int n0 = blockIdx.x * 256 + nq * 4;
    int mbase = blockIdx.y * 16;

    for (int r = 0; r < 16; ++r) {
        const float* Ar = A + (size_t)(mbase + r) * K;
        for (int c = tid; c < K; c += 256) As[r * K + c] = Ar[c];
    }
    __syncthreads();

    float4 bv = *(const float4*)(biasz + n0);
    float acc[4][4];
#pragma unroll
    for (int mi = 0; mi < 4; mi++) { acc[mi][0] = bv.x; acc[mi][1] = bv.y; acc[mi][2] = bv.z; acc[mi][3] = bv.w; }

    const float* asr = As + (mq * 4) * K;
    for (int k = 0; k < K; ++k) {
        float4 w = *(const float4*)(Wtz + (size_t)k * N + n0);
        float x0 = asr[k];
        float x1 = asr[K + k];
        float x2 = asr[2 * K + k];
        float x3 = asr[3 * K + k];
        acc[0][0] += x0 * w.x; acc[0][1] += x0 * w.y; acc[0][2] += x0 * w.z; acc[0][3] += x0 * w.w;
        acc[1][0] += x1 * w.x; acc[1][1] += x1 * w.y; acc[1][2] += x1 * w.z; acc[1][3] += x1 * w.w;
        acc[2][0] += x2 * w.x; acc[2][1] += x2 * w.y; acc[2][2] += x2 * w.z; acc[2][3] += x2 * w.w;
        acc[3][0] += x3 * w.x; acc[3][1] += x3 * w.y; acc[3][2] += x3 * w.z; acc[3][3] += x3 * w.w;
    }
#pragma unroll
    for (int mi = 0; mi < 4; mi++) {
        size_t m = (size_t)mbase + mq * 4 + mi;
        *(float4*)(outz + m * N + n0) = make_float4(acc[mi][0], acc[mi][1], acc[mi][2], acc[mi][3]);
    }
}

// A is bf16 in [t][j][b] layout
__global__ __launch_bounds__(256) void k_gemm_tl(
    const unsigned short* __restrict__ embt, const float* __restrict__ Wt,
    const float* __restrict__ bias, float* __restrict__ out,
    int K, int N)
{
    int z = blockIdx.z;
    const float* Wtz = Wt + (size_t)z * K * N;
    float* outz = out + (size_t)z * 2048 * N;
    const float* biasz = bias + (size_t)z * N;

    __shared__ float As[16 * 512];
    int tid = threadIdx.x;
    int mq = tid >> 6;
    int nq = tid & 63;
    int n0 = blockIdx.x * 256 + nq * 4;
    int mbase = blockIdx.y * 16;
    int bb = mbase >> 7;
    int tt0 = mbase & 127;

    for (int r = 0; r < 16; ++r) {
        const unsigned short* Ar = embt + (size_t)(tt0 + r) * 8192 + bb;
        for (int c = tid; c < K; c += 256) As[r * K + c] = bf2f(Ar[c * 16]);
    }
    __syncthreads();

    float4 bv = *(const float4*)(biasz + n0);
    float acc[4][4];
#pragma unroll
    for (int mi = 0; mi < 4; mi++) { acc[mi][0] = bv.x; acc[mi][1] = bv.y; acc[mi][2] = bv.z; acc[mi][3] = bv.w; }

    const float* asr = As + (mq * 4) * K;
    for (int k = 0; k < K; ++k) {
        float4 w = *(const float4*)(Wtz + (size_t)k * N + n0);
        float x0 = asr[k];
        float x1 = asr[K + k];
        float x2 = asr[2 * K + k];
        float x3 = asr[3 * K + k];
        acc[0][0] += x0 * w.x; acc[0][1] += x0 * w.y; acc[0][2] += x0 * w.z; acc[0][3] += x0 * w.w;
        acc[1][0] += x1 * w.x; acc[1][1] += x1 * w.y; acc[1][2] += x1 * w.z; acc[1][3] += x1 * w.w;
        acc[2][0] += x2 * w.x; acc[2][1] += x2 * w.y; acc[2][2] += x2 * w.z; acc[2][3] += x2 * w.w;
        acc[3][0] += x3 * w.x; acc[3][1] += x3 * w.y; acc[3][2] += x3 * w.z; acc[3][3] += x3 * w.w;
    }
#pragma unroll
    for (int mi = 0; mi < 4; mi++) {
        size_t m = (size_t)mbase + mq * 4 + mi;
        *(float4*)(outz + m * N + n0) = make_float4(acc[mi][0], acc[mi][1], acc[mi][2], acc[mi][3]);
    }
}

// ---------------- MFMA LSTM: j-split across 2 same-XCD blocks per direction --
// 16 blocks launched; registration barrier; same-XCD pairs claim (dir, half);
// extras exit. Each block: 8 slots (j-half): waves 0-3 weights in VGPR (64),
// waves 4-7 from LDS (64 KB conflict-free). Per-step 2KB h-half exchange via
// L2 payload + monotonic flags (memset-reset per launch; bounded spins).
#define GATE8(A, C, H) { \
    float gi = A[0] * 0.015625f, gf = A[1] * 0.015625f, gg = A[2] * 0.015625f, go = A[3] * 0.015625f; \
    float si = __builtin_amdgcn_rcpf(1.f + __expf(-gi)); \
    float sf = __builtin_amdgcn_rcpf(1.f + __expf(-gf)); \
    float so = __builtin_amdgcn_rcpf(1.f + __expf(-go)); \
    float eg = __expf(2.f * gg); \
    float tg = 1.f - 2.f * __builtin_amdgcn_rcpf(eg + 1.f); \
    C = sf * C + si * tg; \
    float ec = __expf(2.f * C); \
    float tc = 1.f - 2.f * __builtin_amdgcn_rcpf(ec + 1.f); \
    H = so * tc; }

__global__ __launch_bounds__(512, 2) void k_lstm_mfma(
    const float* __restrict__ xgf,            // [2][128][16][4][64][4], pre-scaled x64
    const unsigned char* __restrict__ Wfrag8, // [2][16][8][4][64][8] fp8 (k-perm)
    unsigned short* __restrict__ embt,        // [128][512][16] bf16 ([t][j][b])
    int* ctrl,                                // [0]=nreg [1..16]=xcd [16..19]=flags (memset 0)
    unsigned char* pay)                       // [d][half][parity][2048]
{
    const int bid = blockIdx.x;
    const int tid = threadIdx.x;
    const int wv = tid >> 6;      // 0..7
    const int l = tid & 63;
    const int b = l & 15;
    const int jh = l >> 4;

    __shared__ __align__(16) unsigned char Wlds[81920];   // 64KB used + pad -> 1 block/CU
    __shared__ __align__(8) unsigned char hB[4096];
    __shared__ int role_sh[4];

    // ---- registration + same-XCD pairing ----
    if (tid == 0) {
        unsigned xcc = 0;
        asm volatile("s_getreg_b32 %0, hwreg(20, 0, 32)" : "=s"(xcc));
        __hip_atomic_store(&ctrl[1 + bid], (int)(xcc & 7), __ATOMIC_RELAXED, __HIP_MEMORY_SCOPE_AGENT);
        __hip_atomic_fetch_add(&ctrl[0], 1, __ATOMIC_ACQ_REL, __HIP_MEMORY_SCOPE_AGENT);
        long it = 0;
        while (__hip_atomic_load(&ctrl[0], __ATOMIC_ACQUIRE, __HIP_MEMORY_SCOPE_AGENT) < 16 && it < (1 << 24)) {
            ++it; __builtin_amdgcn_s_sleep(2);
        }
        int x[16];
        for (int i = 0; i < 16; ++i)
            x[i] = __hip_atomic_load(&ctrl[1 + i], __ATOMIC_RELAXED, __HIP_MEMORY_SCOPE_AGENT) & 7;
        int pend[8];
        for (int i = 0; i < 8; ++i) pend[i] = -1;
        int np = 0, dd = -1, hh = 0;
        for (int i = 0; i < 16; ++i) {
            int xc = x[i];
            if (pend[xc] < 0) pend[xc] = i;
            else {
                if (np < 2) {
                    if (pend[xc] == bid) { dd = np; hh = 0; }
                    else if (i == bid) { dd = np; hh = 1; }
                }
                np++;
                pend[xc] = -1;
            }
        }
        if (np < 2) {   // fallback: fixed roles, blocks 0..3
            dd = (bid < 4) ? (bid >> 1) : -1;
            hh = bid & 1;
        }
        role_sh[0] = dd; role_sh[1] = hh;
    }
    __syncthreads();
    const int d = role_sh[0];
    const int hh = role_sh[1];
    if (d < 0) return;

    // ---- setup ----
    const int sg = hh * 8 + wv;   // global slot 0..15
    // stage LDS weights: slots hh*8+4 .. hh*8+7 (64 KB)
    {
        const uint4* wsrc = (const uint4*)(Wfrag8 + (size_t)d * 262144 + (size_t)(hh * 8 + 4) * 16384);
        uint4* wdst = (uint4*)Wlds;
        for (int i = tid; i < 4096; i += 512) wdst[i] = wsrc[i];
    }
    ((uint64_t*)hB)[tid] = 0ull;

    long W0[8][4];
    if (wv < 4) {
        const unsigned char* wg0 = Wfrag8 + ((size_t)(d * 16 + sg)) * 16384;
#pragma unroll
        for (int ks = 0; ks < 8; ++ks)
#pragma unroll
            for (int t4 = 0; t4 < 4; ++t4)
                W0[ks][t4] = *(const long*)(wg0 + ((size_t)((ks * 4 + t4) * 64 + l)) * 8);
#pragma unroll
        for (int ks = 0; ks < 8; ++ks)
#pragma unroll
            for (int t4 = 0; t4 < 4; ++t4)
                asm volatile("" : "+v"(W0[ks][t4]));
    }

    const int sgn = d ? -1 : 1;
    int t = d ? 127 : 0;
    const f32x4* xb = (const f32x4*)(xgf) + (size_t)d * 524288;
    const int xo = sg * 256 + l;

    f32x4 a0 = xb[t * 4096 + xo];
    f32x4 a1 = xb[t * 4096 + xo + 64];
    f32x4 a2 = xb[t * 4096 + xo + 128];
    f32x4 a3 = xb[t * 4096 + xo + 192];

    float c0 = 0.f, c1 = 0.f, c2 = 0.f, c3 = 0.f;
    const int hrd = jh * 128 + b * 8;
    const unsigned char* WpL = Wlds + (size_t)(wv - 4) * 16384 + (size_t)l * 8;  // valid for wv>=4
    unsigned short* embp = embt + (size_t)d * 4096 + (size_t)sg * 256 + l;
    unsigned char* hw = hB + sg * 256 + b * 8 + jh * 2;
    int* myflag = &ctrl[16 + d * 2 + hh];
    int* pflag  = &ctrl[16 + d * 2 + (1 - hh)];
    __syncthreads();

    for (int s = 0; s < 128; ++s) {
        if (wv < 4) {
#pragma unroll
            for (int ks = 0; ks < 8; ++ks) {
                long hf = *(const long*)(hB + ks * 512 + hrd);
                a0 = __builtin_amdgcn_mfma_f32_16x16x32_fp8_fp8(W0[ks][0], hf, a0, 0, 0, 0);
                a1 = __builtin_amdgcn_mfma_f32_16x16x32_fp8_fp8(W0[ks][1], hf, a1, 0, 0, 0);
                a2 = __builtin_amdgcn_mfma_f32_16x16x32_fp8_fp8(W0[ks][2], hf, a2, 0, 0, 0);
                a3 = __builtin_amdgcn_mfma_f32_16x16x32_fp8_fp8(W0[ks][3], hf, a3, 0, 0, 0);
            }
        } else {
#pragma unroll
            for (int ks = 0; ks < 8; ++ks) {
                long hf = *(const long*)(hB + ks * 512 + hrd);
                long w0 = *(const long*)(WpL + (ks * 4 + 0) * 512);
                long w1 = *(const long*)(WpL + (ks * 4 + 1) * 512);
                long w2 = *(const long*)(WpL + (ks * 4 + 2) * 512);
                long w3 = *(const long*)(WpL + (ks * 4 + 3) * 512);
                a0 = __builtin_amdgcn_mfma_f32_16x16x32_fp8_fp8(w0, hf, a0, 0, 0, 0);
                a1 = __builtin_amdgcn_mfma_f32_16x16x32_fp8_fp8(w1, hf, a1, 0, 0, 0);
                a2 = __builtin_amdgcn_mfma_f32_16x16x32_fp8_fp8(w2, hf, a2, 0, 0, 0);
                a3 = __builtin_amdgcn_mfma_f32_16x16x32_fp8_fp8(w3, hf, a3, 0, 0, 0);
            }
        }

        float h0, h1, h2, h3;
        GATE8(a0, c0, h0);
        GATE8(a1, c1, h1);
        GATE8(a2, c2, h2);
        GATE8(a3, c3, h3);

        unsigned r01, r23;
        asm("v_cvt_pk_bf16_f32 %0, %1, %2" : "=v"(r01) : "v"(h0), "v"(h1));
        asm("v_cvt_pk_bf16_f32 %0, %1, %2" : "=v"(r23) : "v"(h2), "v"(h3));
        {
            unsigned short* p0 = embp + (size_t)t * 8192;
            p0[0]   = (unsigned short)r01;
            p0[64]  = (unsigned short)(r01 >> 16);
            p0[128] = (unsigned short)r23;
            p0[192] = (unsigned short)(r23 >> 16);
        }
        unsigned q01 = __builtin_amdgcn_cvt_pk_fp8_f32(h0, h1, 0, false);
        unsigned q23 = __builtin_amdgcn_cvt_pk_fp8_f32(h2, h3, 0, false);

        if (s < 127) {
            // payload store (verbatim image of this block's 2KB hB half)
            unsigned char* pw = pay + (((size_t)(d * 2 + hh)) * 2 + (s & 1)) * 2048 + wv * 256 + b * 8 + jh * 2;
            *(unsigned short*)(pw)       = (unsigned short)q01;
            *(unsigned short*)(pw + 128) = (unsigned short)q23;
            asm volatile("s_waitcnt vmcnt(0)" ::: "memory");
            __syncthreads();   // A: all payload stores in L2; all hB reads done

            *(unsigned short*)(hw)       = (unsigned short)q01;
            *(unsigned short*)(hw + 128) = (unsigned short)q23;

            if (tid == 0) {
                __hip_atomic_store(myflag, s + 1, __ATOMIC_RELEASE, __HIP_MEMORY_SCOPE_AGENT);
                int it = 0;
                while (__hip_atomic_load(pflag, __ATOMIC_RELAXED, __HIP_MEMORY_SCOPE_AGENT) <= s && it < (1 << 16)) {
                    ++it; __builtin_amdgcn_s_sleep(1);
                }
                (void)__hip_atomic_load(pflag, __ATOMIC_ACQUIRE, __HIP_MEMORY_SCOPE_AGENT);
            }
            __syncthreads();   // B: partner payload visible

            {
                const unsigned* pr = (const unsigned*)(pay + (((size_t)(d * 2 + (1 - hh))) * 2 + (s & 1)) * 2048);
                unsigned v = __hip_atomic_load(&pr[tid], __ATOMIC_RELAXED, __HIP_MEMORY_SCOPE_AGENT);
                *(unsigned*)(hB + (size_t)(1 - hh) * 2048 + tid * 4) = v;
            }
            // prefetch next step's xg
            int tn = t + sgn;
            a0 = xb[tn * 4096 + xo];
            a1 = xb[tn * 4096 + xo + 64];
            a2 = xb[tn * 4096 + xo + 128];
            a3 = xb[tn * 4096 + xo + 192];
            __syncthreads();   // C: hB complete for s+1
            t = tn;
        }
    }
}

// ---------------- MFMA pairwise scorer (R7 winner, unchanged) ----------------
__global__ __launch_bounds__(256, 2) void k_scorer_mfma(
    const float* __restrict__ HaHb, const unsigned short* __restrict__ w2f,
    const float* __restrict__ b2, const float* __restrict__ W3,
    const float* __restrict__ b3v, float* __restrict__ score)
{
    const int jt = blockIdx.x, it = blockIdx.y, b = blockIdx.z;
    const int j0 = jt * 16, i0 = it * 16;
    const int tid = threadIdx.x;
    const int w = tid >> 6;
    const int l = tid & 63;
    const int n_l = l & 15;
    const int kq = l >> 4;

    __shared__ __align__(16) unsigned short HaS[16 * 264];
    __shared__ __align__(16) unsigned short HbS[16 * 264];

    {
        const float* base = HaHb + ((size_t)(b * 128)) * 512;
        int rr = tid >> 4;
        int q = tid & 15;
#pragma unroll
        for (int rep = 0; rep < 4; ++rep) {
            int k0 = q * 4 + rep * 64;
            float4 va = *(const float4*)(base + (size_t)(i0 + rr) * 512 + k0);
            float4 vb = *(const float4*)(base + (size_t)(j0 + rr) * 512 + 256 + k0);
            u16x4 ua = { f2bf(va.x), f2bf(va.y), f2bf(va.z), f2bf(va.w) };
            u16x4 ub = { f2bf(vb.x), f2bf(vb.y), f2bf(vb.z), f2bf(vb.w) };
            *(u16x4*)(&HaS[rr * 264 + k0]) = ua;
            *(u16x4*)(&HbS[rr * 264 + k0]) = ub;
        }
    }

    float b2v[8], w3v[8];
#pragma unroll
    for (int nt = 0; nt < 8; ++nt) {
        b2v[nt] = b2[nt * 16 + n_l];
        w3v[nt] = W3[nt * 16 + n_l];
    }

    f32x4 acc[4][8];
#pragma unroll
    for (int il = 0; il < 4; ++il)
#pragma unroll
        for (int nt = 0; nt < 8; ++nt) acc[il][nt] = f32x4{0.f, 0.f, 0.f, 0.f};

    const bf16x8* wbase = (const bf16x8*)w2f;
    bf16x8 wf[8], wfn[8];
#pragma unroll
    for (int nt = 0; nt < 8; ++nt) wf[nt] = wbase[(nt * 8 + 0) * 64 + l];

    __syncthreads();

#pragma unroll
    for (int ks = 0; ks < 8; ++ks) {
        if (ks < 7) {
#pragma unroll
            for (int nt = 0; nt < 8; ++nt) wfn[nt] = wbase[(nt * 8 + ks + 1) * 64 + l];
        }
#pragma unroll
        for (int il = 0; il < 4; ++il) {
            const int irow = w * 4 + il;
            bf16x8 ha = *(const bf16x8*)(&HaS[irow * 264 + ks * 32 + kq * 8]);
            bf16x8 hb = *(const bf16x8*)(&HbS[n_l * 264 + ks * 32 + kq * 8]);
            bf16x8 av;
#pragma unroll
            for (int e = 0; e < 8; ++e) {
                float v = bf2f((unsigned short)ha[e]) + bf2f((unsigned short)hb[e]);
                v = v > 0.f ? v : 0.f;
                av[e] = (short)f2bf(v);
            }
#pragma unroll
            for (int nt = 0; nt < 8; ++nt)
                acc[il][nt] = __builtin_amdgcn_mfma_f32_16x16x32_bf16(av, wf[nt], acc[il][nt], 0, 0, 0);
        }
#pragma unroll
        for (int nt = 0; nt < 8; ++nt) wf[nt] = wfn[nt];
    }

    const float bb3 = b3v[0];
#pragma unroll
    for (int il = 0; il < 4; ++il) {
        float p[4];
#pragma unroll
        for (int reg = 0; reg < 4; ++reg) {
            float v = 0.f;
#pragma unroll
            for (int nt = 0; nt < 8; ++nt) {
                float h2v = acc[il][nt][reg] + b2v[nt];
                h2v = h2v > 0.f ? h2v : 0.f;
                v += h2v * w3v[nt];
            }
            p[reg] = v;
        }
#pragma unroll
        for (int m = 1; m < 16; m <<= 1) {
            p[0] += __shfl_xor(p[0], m);
            p[1] += __shfl_xor(p[1], m);
            p[2] += __shfl_xor(p[2], m);
            p[3] += __shfl_xor(p[3], m);
        }
        if (n_l == 0) {
            const int i = i0 + w * 4 + il;
            const int jb = j0 + kq * 4;
            float4 sv;
            float* pv = &sv.x;
#pragma unroll
            for (int reg = 0; reg < 4; ++reg) {
                int jg = jb + reg;
                float sc = p[reg] + bb3;
                sc = sc > 0.f ? sc : 0.f;
                if (jg == i || jg == 0) sc = 0.f;
                pv[reg] = sc;
            }
            *(float4*)(&score[((size_t)(b * 128 + i)) * 128 + jb]) = sv;
        }
    }
}

// ---------------- loss ----------------
__global__ __launch_bounds__(128) void k_loss1(
    const float* __restrict__ score, const int* __restrict__ tree, float* __restrict__ res)
{
    int k = blockIdx.x;
    int b = blockIdx.y;
    int head = tree[((size_t)b * 128 + k + 1) * 2 + 0];
    int dep  = tree[((size_t)b * 128 + k + 1) * 2 + 1];
    int i = threadIdx.x;
    float s = score[((size_t)b * 128 + i) * 128 + dep];
    float v = (i == dep) ? 0.f : __expf(s);
    __shared__ float redu[2];
#pragma unroll
    for (int off = 32; off >= 1; off >>= 1) v += __shfl_down(v, off, 64);
    if ((i & 63) == 0) redu[i >> 6] = v;
    __syncthreads();
    if (i == 0) {
        float norm = redu[0] + redu[1];
        float num = score[((size_t)b * 128 + head) * 128 + dep];
        res[b * 127 + k] = __logf(norm) - num;
    }
}

__global__ __launch_bounds__(256) void k_loss2(const float* __restrict__ res, float* __restrict__ out) {
    int tid = threadIdx.x;
    float a = 0.f;
    for (int idx = tid; idx < 16 * 127; idx += 256) a += res[idx];
    __shared__ float sm[256];
    sm[tid] = a;
    __syncthreads();
    for (int off = 128; off >= 1; off >>= 1) {
        if (tid < off) sm[tid] += sm[tid + off];
        __syncthreads();
    }
    if (tid == 0) out[0] = sm[0] / 127.f;
}

// ---------------- host launcher ----------------
extern "C" void kernel_launch(void* const* d_in, const int* in_sizes, int n_in,
                              void* d_out, int out_size, void* d_ws, size_t ws_size,
                              hipStream_t stream) {
    (void)in_sizes; (void)n_in; (void)out_size; (void)ws_size;
    const float* X    = (const float*)d_in[0];
    const float* Wih0 = (const float*)d_in[1];
    const float* Whh0 = (const float*)d_in[2];
    const float* bih0 = (const float*)d_in[3];
    const float* bhh0 = (const float*)d_in[4];
    const float* Wih1 = (const float*)d_in[5];
    const float* Whh1 = (const float*)d_in[6];
    const float* bih1 = (const float*)d_in[7];
    const float* bhh1 = (const float*)d_in[8];
    const float* W1   = (const float*)d_in[9];
    const float* b1   = (const float*)d_in[10];
    const float* W2   = (const float*)d_in[11];
    const float* b2   = (const float*)d_in[12];
    const float* W3   = (const float*)d_in[13];
    const float* b3   = (const float*)d_in[14];
    const int*   tree = (const int*)d_in[15];
    float* out = (float*)d_out;   // [0]=loss, [1..]=score

    float* ws = (float*)d_ws;
    size_t o = 0;
    float* WihT0 = ws + o; o += (size_t)2 * 200 * 1024;
    float* WihT1 = ws + o; o += (size_t)2 * 512 * 1024;
    float* W1T   = ws + o; o += (size_t)512 * 512;
    float* bsum0 = ws + o; o += 2048;
    float* bsum1 = ws + o; o += 2048;
    float* bhab  = ws + o; o += 512;
    unsigned char* Wf0 = (unsigned char*)(ws + o); o += (size_t)2 * 16 * 8 * 4 * 64 * 8 / 4;
    unsigned char* Wf1 = (unsigned char*)(ws + o); o += (size_t)2 * 16 * 8 * 4 * 64 * 8 / 4;
    unsigned short* w2f = (unsigned short*)(ws + o); o += (size_t)8 * 8 * 64 * 8 / 2;
    float* xg   = ws + o; o += (size_t)2 * 2048 * 1024;
    float* xgf  = ws + o; o += (size_t)2 * 2048 * 1024;
    unsigned short* embt0 = (unsigned short*)(ws + o); o += (size_t)128 * 512 * 16 / 2;
    unsigned short* embt1 = (unsigned short*)(ws + o); o += (size_t)128 * 512 * 16 / 2;
    float* HaHb = ws + o; o += (size_t)2048 * 512;
    float* res  = ws + o; o += 2048;
    int* ctrl = (int*)(ws + o); o += 32;
    unsigned char* pay = (unsigned char*)(ws + o); o += 4096;   // 16 KB

    // prep
    k_transpose_N1024<<<dim3(800, 1, 2), 256, 0, stream>>>(Wih0, WihT0, 200);
    k_transpose_N1024<<<dim3(2048, 1, 2), 256, 0, stream>>>(Wih1, WihT1, 512);
    k_wfrag8<<<256, 256, 0, stream>>>(Whh0, Wf0);
    k_wfrag8<<<256, 256, 0, stream>>>(Whh1, Wf1);
    k_w2frag<<<16, 256, 0, stream>>>(W2, w2f);
    k_w1t<<<1024, 256, 0, stream>>>(W1, W1T);
    k_bias<<<18, 256, 0, stream>>>(bih0, bhh0, bih1, bhh1, b1, bsum0, bsum1, bhab);

    // layer 0
    k_gemm<<<dim3(4, 128, 2), 256, 0, stream>>>(X, WihT0, bsum0, xg, 2048, 200, 1024);
    k_reorder<<<4096, 256, 0, stream>>>(xg, xgf);
    hipMemsetAsync(ctrl, 0, 128, stream);
    k_lstm_mfma<<<16, 512, 0, stream>>>(xgf, Wf0, embt0, ctrl, pay);
    // layer 1
    k_gemm_tl<<<dim3(4, 128, 2), 256, 0, stream>>>(embt0, WihT1, bsum1, xg, 512, 1024);
    k_reorder<<<4096, 256, 0, stream>>>(xg, xgf);
    hipMemsetAsync(ctrl, 0, 128, stream);
    k_lstm_mfma<<<16, 512, 0, stream>>>(xgf, Wf1, embt1, ctrl, pay);
    // Ha|Hb
    k_gemm_tl<<<dim3(2, 128, 1), 256, 0, stream>>>(embt1, W1T, bhab, HaHb, 512, 512);
    // scorer -> out+1
    k_scorer_mfma<<<dim3(8, 8, 16), 256, 0, stream>>>(HaHb, w2f, b2, W3, b3, out + 1);
    // loss
    k_loss1<<<dim3(127, 16), 128, 0, stream>>>(out + 1, tree, res);
    k_loss2<<<1, 256, 0, stream>>>(res, out);
}

// Round 16
// 679.988 us; speedup vs baseline: 1.3480x; 1.3480x over previous
//
#include <hip/hip_runtime.h>
#include <hip/hip_bf16.h>
#include <cstdint>
#include <cstddef>

// B=16, S=128, IN=200, H=256, 4H=1024, 2H=512

typedef __attribute__((ext_vector_type(8))) short bf16x8;
typedef __attribute__((ext_vector_type(4))) float f32x4;
typedef __attribute__((ext_vector_type(4))) unsigned short u16x4;

__device__ __forceinline__ float bf2f(unsigned short u) {
    return __uint_as_float(((unsigned)u) << 16);
}
__device__ __forceinline__ unsigned short f2bf(float f) {
    unsigned u = __float_as_uint(f);
    u = (u + 0x7FFFu + ((u >> 16) & 1u)) >> 16;
    return (unsigned short)u;
}

// float -> OCP e4m3fn with RNE (prep only)
__device__ __forceinline__ unsigned f2e4m3(float f) {
    unsigned u = __float_as_uint(f);
    unsigned s = (u >> 24) & 0x80u;
    int expf_ = (int)((u >> 23) & 0xFF);
    if (expf_ == 0) return s;
    int exp = expf_ - 127;
    if (exp < -10) return s;
    unsigned M = (u & 0x7FFFFF) | 0x800000;
    int e8 = exp + 7;
    int shift = 20;
    if (e8 < 1) { shift = 21 - e8; e8 = 0; }
    unsigned q = M >> shift;
    unsigned rem = M & ((1u << shift) - 1u);
    unsigned half = 1u << (shift - 1);
    if (rem > half || (rem == half && (q & 1))) q++;
    if (q >= 16) { q >>= 1; e8++; }
    if (e8 == 0 && (q & 8)) e8 = 1;
    if (e8 >= 16 || (e8 == 15 && (q & 7) == 7)) return s | 0x7Eu;
    return s | ((unsigned)e8 << 4) | (q & 7u);
}

// ---------------- prep kernels ----------------

// dst[z][k][n] = src[z][n][k], n<1024, k<K   (used for Wih0 only)
__global__ void k_transpose_N1024(const float* __restrict__ src, float* __restrict__ dst, int K) {
    int z = blockIdx.z;
    int idx = blockIdx.x * 256 + threadIdx.x;
    if (idx >= K * 1024) return;
    int k = idx >> 10, n = idx & 1023;
    dst[(size_t)z * K * 1024 + idx] = src[(size_t)z * 1024 * K + (size_t)n * K + k];
}

// Whh -> fp8 A-fragments of 64*Whh, k-perm cOf(e)=(e&1)*4+(e>>1)  (R11 layout)
__global__ void k_wfrag8(const float* __restrict__ Whh, unsigned char* __restrict__ Wfrag8) {
    int idx = blockIdx.x * 256 + threadIdx.x;   // 65536 total
    int l = idx & 63;
    int t = (idx >> 6) & 3;
    int ks = (idx >> 8) & 7;
    int w = (idx >> 11) & 15;
    int d = idx >> 15;
    int r = l & 15;
    int kbase = ks * 32 + (l >> 4) * 8;
    int row = (r & 3) * 256 + w * 16 + t * 4 + (r >> 2);
    const float* src = Whh + (size_t)d * (1024 * 256) + (size_t)row * 256 + kbase;
    unsigned char* dst = Wfrag8 + (size_t)idx * 8;
#pragma unroll
    for (int e = 0; e < 8; ++e) {
        int c = (e & 1) * 4 + (e >> 1);
        dst[e] = (unsigned char)f2e4m3(64.f * src[c]);
    }
}

// W2 (128,256) fp32 -> B-fragment layout bf16 (scorer)
__global__ void k_w2frag(const float* __restrict__ W2, unsigned short* __restrict__ w2f) {
    int idx = blockIdx.x * 256 + threadIdx.x;   // 4096 total
    if (idx >= 4096) return;
    int l = idx & 63;
    int ks = (idx >> 6) & 7;
    int nt = idx >> 9;
    const float* src = W2 + (size_t)(nt * 16 + (l & 15)) * 256 + ks * 32 + (l >> 4) * 8;
    unsigned short* dst = w2f + (size_t)idx * 8;
#pragma unroll
    for (int e = 0; e < 8; ++e) dst[e] = f2bf(src[e]);
}

// Wih1 (2,1024,512) -> mgemm B-frags bf16: wf[((z*16+ks)*64+nt)*64+l][e] =
//   bf16(Wih1[z][nt*16+(l&15)][ks*32+(l>>4)*8+e])
__global__ void k_wfragb_ih1(const float* __restrict__ Wih1, unsigned short* __restrict__ wf) {
    int o = blockIdx.x * 256 + threadIdx.x;   // 131072 total
    int l = o & 63;
    int nt = (o >> 6) & 63;
    int ks = (o >> 12) & 15;
    int z = o >> 16;
    int n = nt * 16 + (l & 15);
    int k0 = ks * 32 + (l >> 4) * 8;
    const float* src = Wih1 + ((size_t)z * 1024 + n) * 512 + k0;
    unsigned short* dst = wf + (size_t)o * 8;
#pragma unroll
    for (int e = 0; e < 8; ++e) dst[e] = f2bf(src[e]);
}

// W1 (256,1024) -> mgemm B-frags bf16 for Ha|Hb (N=512):
// wf[(ks*32+nt)*64+l][e] = bf16(W1T[k][o]) with W1T[k][o] = o<256?W1[o][k]:W1[o-256][512+k]
__global__ void k_wfragb_w1(const float* __restrict__ W1, unsigned short* __restrict__ wf) {
    int o = blockIdx.x * 256 + threadIdx.x;   // 32768 total
    int l = o & 63;
    int nt = (o >> 6) & 31;
    int ks = o >> 11;
    int oc = nt * 16 + (l & 15);
    int k0 = ks * 32 + (l >> 4) * 8;
    unsigned short* dst = wf + (size_t)o * 8;
#pragma unroll
    for (int e = 0; e < 8; ++e) {
        int k = k0 + e;
        float v = (oc < 256) ? W1[(size_t)oc * 1024 + k] : W1[(size_t)(oc - 256) * 1024 + 512 + k];
        dst[e] = f2bf(v);
    }
}

__global__ void k_bias(const float* __restrict__ bih0, const float* __restrict__ bhh0,
                       const float* __restrict__ bih1, const float* __restrict__ bhh1,
                       const float* __restrict__ b1,
                       float* __restrict__ bsum0, float* __restrict__ bsum1, float* __restrict__ bhab) {
    int idx = blockIdx.x * 256 + threadIdx.x;
    if (idx < 2048) bsum0[idx] = bih0[idx] + bhh0[idx];
    else if (idx < 4096) { int i = idx - 2048; bsum1[i] = bih1[i] + bhh1[i]; }
    else if (idx < 4608) { int i = idx - 4096; bhab[i] = (i < 256) ? b1[i] : 0.f; }
}

// xg -> xgfrag, PRE-SCALED by 64
__global__ __launch_bounds__(256) void k_reorder(const float* __restrict__ xg, float* __restrict__ xgf) {
    int idx = blockIdx.x * 256 + threadIdx.x;   // 1048576 total
    int n4 = idx & 255;
    int m = (idx >> 8) & 2047;
    int d = idx >> 19;
    int n0 = n4 * 4;
    int q = n0 >> 8;
    int jbase = n0 & 255;
    int b = m >> 7, t = m & 127;
    float4 v = *(const float4*)(xg + ((size_t)(d * 2048 + m)) * 1024 + n0);
    float* base = xgf + (size_t)d * 2097152;
    float vv[4] = {v.x * 64.f, v.y * 64.f, v.z * 64.f, v.w * 64.f};
#pragma unroll
    for (int dj = 0; dj < 4; ++dj) {
        int j = jbase + dj;
        int fi = (t * 4096 + (j >> 4) * 256 + ((j >> 2) & 3) * 64 + dj * 16 + b) * 4 + q;
        base[fi] = vv[dj];
    }
}

// embt [t][j][b] -> embR [m=b*128+t][j] row-major bf16. Both sides coalesced.
__global__ __launch_bounds__(256) void k_embR(const unsigned short* __restrict__ embt,
                                              unsigned short* __restrict__ embR) {
    int t = blockIdx.x;
    for (int j = threadIdx.x; j < 512; j += 256) {
        uint4 v = *(const uint4*)(embt + (size_t)t * 8192 + j * 16);
        const unsigned short* pv = (const unsigned short*)&v;
#pragma unroll
        for (int b = 0; b < 16; ++b)
            embR[((size_t)(b * 128 + t)) * 512 + j] = pv[b];
    }
}

// ---------------- fp32 GEMM for layer 0 (A fp32, K=200) ----------------
__global__ __launch_bounds__(256) void k_gemm(
    const float* __restrict__ A, const float* __restrict__ Wt,
    const float* __restrict__ bias, float* __restrict__ out,
    int M, int K, int N)
{
    int z = blockIdx.z;
    const float* Wtz = Wt + (size_t)z * K * N;
    float* outz = out + (size_t)z * M * N;
    const float* biasz = bias + (size_t)z * N;

    __shared__ float As[16 * 512];
    int tid = threadIdx.x;
    int mq = tid >> 6;
    int nq = tid & 63;
    int n0 = blockIdx.x * 256 + nq * 4;
    int mbase = blockIdx.y * 16;

    for (int r = 0; r < 16; ++r) {
        const float* Ar = A + (size_t)(mbase + r) * K;
        for (int c = tid; c < K; c += 256) As[r * K + c] = Ar[c];
    }
    __syncthreads();

    float4 bv = *(const float4*)(biasz + n0);
    float acc[4][4];
#pragma unroll
    for (int mi = 0; mi < 4; mi++) { acc[mi][0] = bv.x; acc[mi][1] = bv.y; acc[mi][2] = bv.z; acc[mi][3] = bv.w; }

    const float* asr = As + (mq * 4) * K;
    for (int k = 0; k < K; ++k) {
        float4 w = *(const float4*)(Wtz + (size_t)k * N + n0);
        float x0 = asr[k];
        float x1 = asr[K + k];
        float x2 = asr[2 * K + k];
        float x3 = asr[3 * K + k];
        acc[0][0] += x0 * w.x; acc[0][1] += x0 * w.y; acc[0][2] += x0 * w.z; acc[0][3] += x0 * w.w;
        acc[1][0] += x1 * w.x; acc[1][1] += x1 * w.y; acc[1][2] += x1 * w.z; acc[1][3] += x1 * w.w;
        acc[2][0] += x2 * w.x; acc[2][1] += x2 * w.y; acc[2][2] += x2 * w.z; acc[2][3] += x2 * w.w;
        acc[3][0] += x3 * w.x; acc[3][1] += x3 * w.y; acc[3][2] += x3 * w.z; acc[3][3] += x3 * w.w;
    }
#pragma unroll
    for (int mi = 0; mi < 4; mi++) {
        size_t m = (size_t)mbase + mq * 4 + mi;
        *(float4*)(outz + m * N + n0) = make_float4(acc[mi][0], acc[mi][1], acc[mi][2], acc[mi][3]);
    }
}

// ---------------- MFMA GEMM: out[z][m][n] = bias[z][n] + embR[m][:] . wf ----
// M=2048, K=512 fixed. grid (N/256, 32, z), 256 thr (4 waves).
// Wave w: 4 n-tiles at blockIdx.x*16 + w*4. Per wave 4m x 4n acc tiles.
__global__ __launch_bounds__(256) void k_mgemm(
    const unsigned short* __restrict__ embR, // [2048][512] bf16
    const unsigned short* __restrict__ wf,   // [z][16][N/16][64][8] bf16
    const float* __restrict__ bias,          // [z][N]
    float* __restrict__ out,                 // [z][2048][N]
    int N)
{
    const int z = blockIdx.z;
    const int NT = N >> 4;
    const int tid = threadIdx.x;
    const int w = tid >> 6;
    const int l = tid & 63;
    const int arow = l & 15;      // A-frag row / C col
    const int kq = l >> 4;
    const int mbase = blockIdx.y * 64;
    const int ntb = blockIdx.x * 16 + w * 4;

    __shared__ __align__(16) unsigned short As[64 * 520];

    // stage A tile (64 x 512), coalesced 16B both sides, 2-way LDS banks
    for (int i = tid; i < 4096; i += 256) {
        int r = i >> 6, k8 = i & 63;
        *(bf16x8*)(&As[r * 520 + k8 * 8]) =
            *(const bf16x8*)(embR + (size_t)(mbase + r) * 512 + k8 * 8);
    }

    const bf16x8* wb = (const bf16x8*)wf + (size_t)z * 16 * NT * 64;
    bf16x8 bf[4], bfn[4];
#pragma unroll
    for (int ntl = 0; ntl < 4; ++ntl) bf[ntl] = wb[(size_t)(0 * NT + ntb + ntl) * 64 + l];

    f32x4 acc[4][4];
#pragma unroll
    for (int ntl = 0; ntl < 4; ++ntl) {
        float bv = bias[(size_t)z * N + (ntb + ntl) * 16 + arow];
#pragma unroll
        for (int mt = 0; mt < 4; ++mt) acc[mt][ntl] = f32x4{bv, bv, bv, bv};
    }
    __syncthreads();

#pragma unroll
    for (int ks = 0; ks < 16; ++ks) {
        if (ks < 15) {
#pragma unroll
            for (int ntl = 0; ntl < 4; ++ntl)
                bfn[ntl] = wb[(size_t)((ks + 1) * NT + ntb + ntl) * 64 + l];
        }
        bf16x8 af[4];
#pragma unroll
        for (int mt = 0; mt < 4; ++mt)
            af[mt] = *(const bf16x8*)(&As[(mt * 16 + arow) * 520 + ks * 32 + kq * 8]);
#pragma unroll
        for (int mt = 0; mt < 4; ++mt)
#pragma unroll
            for (int ntl = 0; ntl < 4; ++ntl)
                acc[mt][ntl] = __builtin_amdgcn_mfma_f32_16x16x32_bf16(af[mt], bf[ntl], acc[mt][ntl], 0, 0, 0);
#pragma unroll
        for (int ntl = 0; ntl < 4; ++ntl) bf[ntl] = bfn[ntl];
    }

    // epilogue: C row = mbase+mt*16+kq*4+reg, col = (ntb+ntl)*16+arow
    float* oz = out + (size_t)z * 2048 * N;
#pragma unroll
    for (int mt = 0; mt < 4; ++mt)
#pragma unroll
        for (int ntl = 0; ntl < 4; ++ntl) {
            int ncol = (ntb + ntl) * 16 + arow;
#pragma unroll
            for (int reg = 0; reg < 4; ++reg) {
                int m = mbase + mt * 16 + kq * 4 + reg;
                oz[(size_t)m * N + ncol] = acc[mt][ntl][reg];
            }
        }
}

// ---------------- MFMA LSTM recurrence (R11 exact, measured-best 252us) ----
#define GATE8(A, C, H) { \
    float gi = A[0] * 0.015625f, gf = A[1] * 0.015625f, gg = A[2] * 0.015625f, go = A[3] * 0.015625f; \
    float si = __builtin_amdgcn_rcpf(1.f + __expf(-gi)); \
    float sf = __builtin_amdgcn_rcpf(1.f + __expf(-gf)); \
    float so = __builtin_amdgcn_rcpf(1.f + __expf(-go)); \
    float eg = __expf(2.f * gg); \
    float tg = 1.f - 2.f * __builtin_amdgcn_rcpf(eg + 1.f); \
    C = sf * C + si * tg; \
    float ec = __expf(2.f * C); \
    float tc = 1.f - 2.f * __builtin_amdgcn_rcpf(ec + 1.f); \
    H = so * tc; }

__global__ __launch_bounds__(512, 2) void k_lstm_mfma(
    const float* __restrict__ xgf,            // [2][128][16][4][64][4], pre-scaled x64
    const unsigned char* __restrict__ Wfrag8, // [2][16][8][4][64][8] fp8 of 64*Whh (k-perm)
    unsigned short* __restrict__ embt)        // [128][512][16] bf16 ([t][j][b])
{
    const int d = blockIdx.x;
    const int tid = threadIdx.x;
    const int wv = tid >> 6;      // 0..7
    const int l = tid & 63;
    const int b = l & 15;
    const int jh = l >> 4;
    const int s0 = wv * 2, s1 = wv * 2 + 1;

    __shared__ __align__(8) unsigned char hB[4096];   // fp8 h, single buffer

    const unsigned char* wg0 = Wfrag8 + ((size_t)(d * 16 + s0)) * 16384;
    const unsigned char* wg1 = Wfrag8 + ((size_t)(d * 16 + s1)) * 16384;
    long W0[8][4], W1[8][4];
#pragma unroll
    for (int ks = 0; ks < 8; ++ks)
#pragma unroll
        for (int t4 = 0; t4 < 4; ++t4) {
            W0[ks][t4] = *(const long*)(wg0 + ((size_t)((ks * 4 + t4) * 64 + l)) * 8);
            W1[ks][t4] = *(const long*)(wg1 + ((size_t)((ks * 4 + t4) * 64 + l)) * 8);
        }
#pragma unroll
    for (int ks = 0; ks < 8; ++ks)
#pragma unroll
        for (int t4 = 0; t4 < 4; ++t4) {
            asm volatile("" : "+v"(W0[ks][t4]));
            asm volatile("" : "+v"(W1[ks][t4]));
        }

    ((uint64_t*)hB)[tid] = 0ull;

    const int sgn = d ? -1 : 1;
    int t = d ? 127 : 0;
    const f32x4* xb = (const f32x4*)(xgf) + (size_t)d * 524288;
    const int xo0 = s0 * 256 + l;
    const int xo1 = s1 * 256 + l;

    f32x4 a0 = xb[t * 4096 + xo0];
    f32x4 a1 = xb[t * 4096 + xo0 + 64];
    f32x4 a2 = xb[t * 4096 + xo0 + 128];
    f32x4 a3 = xb[t * 4096 + xo0 + 192];
    f32x4 e0 = xb[t * 4096 + xo1];
    f32x4 e1 = xb[t * 4096 + xo1 + 64];
    f32x4 e2 = xb[t * 4096 + xo1 + 128];
    f32x4 e3 = xb[t * 4096 + xo1 + 192];

    float c0 = 0.f, c1 = 0.f, c2 = 0.f, c3 = 0.f;
    float c4 = 0.f, c5 = 0.f, c6 = 0.f, c7 = 0.f;
    const int hrd = jh * 128 + b * 8;
    unsigned short* ep0 = embt + (size_t)d * 4096 + (size_t)s0 * 256 + l;
    unsigned short* ep1 = embt + (size_t)d * 4096 + (size_t)s1 * 256 + l;
    unsigned char* hw0 = hB + s0 * 256 + b * 8 + jh * 2;
    unsigned char* hw1 = hB + s1 * 256 + b * 8 + jh * 2;
    __syncthreads();

    for (int s = 0; s < 128; ++s) {
#pragma unroll
        for (int ks = 0; ks < 8; ++ks) {
            long hf = *(const long*)(hB + ks * 512 + hrd);
            a0 = __builtin_amdgcn_mfma_f32_16x16x32_fp8_fp8(W0[ks][0], hf, a0, 0, 0, 0);
            a1 = __builtin_amdgcn_mfma_f32_16x16x32_fp8_fp8(W0[ks][1], hf, a1, 0, 0, 0);
            a2 = __builtin_amdgcn_mfma_f32_16x16x32_fp8_fp8(W0[ks][2], hf, a2, 0, 0, 0);
            a3 = __builtin_amdgcn_mfma_f32_16x16x32_fp8_fp8(W0[ks][3], hf, a3, 0, 0, 0);
            e0 = __builtin_amdgcn_mfma_f32_16x16x32_fp8_fp8(W1[ks][0], hf, e0, 0, 0, 0);
            e1 = __builtin_amdgcn_mfma_f32_16x16x32_fp8_fp8(W1[ks][1], hf, e1, 0, 0, 0);
            e2 = __builtin_amdgcn_mfma_f32_16x16x32_fp8_fp8(W1[ks][2], hf, e2, 0, 0, 0);
            e3 = __builtin_amdgcn_mfma_f32_16x16x32_fp8_fp8(W1[ks][3], hf, e3, 0, 0, 0);
        }

        float h0, h1, h2, h3, h4, h5, h6, h7;
        GATE8(a0, c0, h0);
        GATE8(a1, c1, h1);
        GATE8(a2, c2, h2);
        GATE8(a3, c3, h3);
        GATE8(e0, c4, h4);
        GATE8(e1, c5, h5);
        GATE8(e2, c6, h6);
        GATE8(e3, c7, h7);

        unsigned r01, r23, r45, r67;
        asm("v_cvt_pk_bf16_f32 %0, %1, %2" : "=v"(r01) : "v"(h0), "v"(h1));
        asm("v_cvt_pk_bf16_f32 %0, %1, %2" : "=v"(r23) : "v"(h2), "v"(h3));
        asm("v_cvt_pk_bf16_f32 %0, %1, %2" : "=v"(r45) : "v"(h4), "v"(h5));
        asm("v_cvt_pk_bf16_f32 %0, %1, %2" : "=v"(r67) : "v"(h6), "v"(h7));
        {
            unsigned short* p0 = ep0 + (size_t)t * 8192;
            p0[0]   = (unsigned short)r01;
            p0[64]  = (unsigned short)(r01 >> 16);
            p0[128] = (unsigned short)r23;
            p0[192] = (unsigned short)(r23 >> 16);
            unsigned short* p1 = ep1 + (size_t)t * 8192;
            p1[0]   = (unsigned short)r45;
            p1[64]  = (unsigned short)(r45 >> 16);
            p1[128] = (unsigned short)r67;
            p1[192] = (unsigned short)(r67 >> 16);
        }

        unsigned q01 = __builtin_amdgcn_cvt_pk_fp8_f32(h0, h1, 0, false);
        unsigned q23 = __builtin_amdgcn_cvt_pk_fp8_f32(h2, h3, 0, false);
        unsigned q45 = __builtin_amdgcn_cvt_pk_fp8_f32(h4, h5, 0, false);
        unsigned q67 = __builtin_amdgcn_cvt_pk_fp8_f32(h6, h7, 0, false);

        int tn = (s == 127) ? t : (t + sgn);
        a0 = xb[tn * 4096 + xo0];
        a1 = xb[tn * 4096 + xo0 + 64];
        a2 = xb[tn * 4096 + xo0 + 128];
        a3 = xb[tn * 4096 + xo0 + 192];
        e0 = xb[tn * 4096 + xo1];
        e1 = xb[tn * 4096 + xo1 + 64];
        e2 = xb[tn * 4096 + xo1 + 128];
        e3 = xb[tn * 4096 + xo1 + 192];
        __syncthreads();
        *(unsigned short*)(hw0)       = (unsigned short)q01;
        *(unsigned short*)(hw0 + 128) = (unsigned short)q23;
        *(unsigned short*)(hw1)       = (unsigned short)q45;
        *(unsigned short*)(hw1 + 128) = (unsigned short)q67;
        __syncthreads();
        t = tn;
    }
}

// ---------------- MFMA pairwise scorer (R7 winner, unchanged) ----------------
__global__ __launch_bounds__(256, 2) void k_scorer_mfma(
    const float* __restrict__ HaHb, const unsigned short* __restrict__ w2f,
    const float* __restrict__ b2, const float* __restrict__ W3,
    const float* __restrict__ b3v, float* __restrict__ score)
{
    const int jt = blockIdx.x, it = blockIdx.y, b = blockIdx.z;
    const int j0 = jt * 16, i0 = it * 16;
    const int tid = threadIdx.x;
    const int w = tid >> 6;
    const int l = tid & 63;
    const int n_l = l & 15;
    const int kq = l >> 4;

    __shared__ __align__(16) unsigned short HaS[16 * 264];
    __shared__ __align__(16) unsigned short HbS[16 * 264];

    {
        const float* base = HaHb + ((size_t)(b * 128)) * 512;
        int rr = tid >> 4;
        int q = tid & 15;
#pragma unroll
        for (int rep = 0; rep < 4; ++rep) {
            int k0 = q * 4 + rep * 64;
            float4 va = *(const float4*)(base + (size_t)(i0 + rr) * 512 + k0);
            float4 vb = *(const float4*)(base + (size_t)(j0 + rr) * 512 + 256 + k0);
            u16x4 ua = { f2bf(va.x), f2bf(va.y), f2bf(va.z), f2bf(va.w) };
            u16x4 ub = { f2bf(vb.x), f2bf(vb.y), f2bf(vb.z), f2bf(vb.w) };
            *(u16x4*)(&HaS[rr * 264 + k0]) = ua;
            *(u16x4*)(&HbS[rr * 264 + k0]) = ub;
        }
    }

    float b2v[8], w3v[8];
#pragma unroll
    for (int nt = 0; nt < 8; ++nt) {
        b2v[nt] = b2[nt * 16 + n_l];
        w3v[nt] = W3[nt * 16 + n_l];
    }

    f32x4 acc[4][8];
#pragma unroll
    for (int il = 0; il < 4; ++il)
#pragma unroll
        for (int nt = 0; nt < 8; ++nt) acc[il][nt] = f32x4{0.f, 0.f, 0.f, 0.f};

    const bf16x8* wbase = (const bf16x8*)w2f;
    bf16x8 wf[8], wfn[8];
#pragma unroll
    for (int nt = 0; nt < 8; ++nt) wf[nt] = wbase[(nt * 8 + 0) * 64 + l];

    __syncthreads();

#pragma unroll
    for (int ks = 0; ks < 8; ++ks) {
        if (ks < 7) {
#pragma unroll
            for (int nt = 0; nt < 8; ++nt) wfn[nt] = wbase[(nt * 8 + ks + 1) * 64 + l];
        }
#pragma unroll
        for (int il = 0; il < 4; ++il) {
            const int irow = w * 4 + il;
            bf16x8 ha = *(const bf16x8*)(&HaS[irow * 264 + ks * 32 + kq * 8]);
            bf16x8 hb = *(const bf16x8*)(&HbS[n_l * 264 + ks * 32 + kq * 8]);
            bf16x8 av;
#pragma unroll
            for (int e = 0; e < 8; ++e) {
                float v = bf2f((unsigned short)ha[e]) + bf2f((unsigned short)hb[e]);
                v = v > 0.f ? v : 0.f;
                av[e] = (short)f2bf(v);
            }
#pragma unroll
            for (int nt = 0; nt < 8; ++nt)
                acc[il][nt] = __builtin_amdgcn_mfma_f32_16x16x32_bf16(av, wf[nt], acc[il][nt], 0, 0, 0);
        }
#pragma unroll
        for (int nt = 0; nt < 8; ++nt) wf[nt] = wfn[nt];
    }

    const float bb3 = b3v[0];
#pragma unroll
    for (int il = 0; il < 4; ++il) {
        float p[4];
#pragma unroll
        for (int reg = 0; reg < 4; ++reg) {
            float v = 0.f;
#pragma unroll
            for (int nt = 0; nt < 8; ++nt) {
                float h2v = acc[il][nt][reg] + b2v[nt];
                h2v = h2v > 0.f ? h2v : 0.f;
                v += h2v * w3v[nt];
            }
            p[reg] = v;
        }
#pragma unroll
        for (int m = 1; m < 16; m <<= 1) {
            p[0] += __shfl_xor(p[0], m);
            p[1] += __shfl_xor(p[1], m);
            p[2] += __shfl_xor(p[2], m);
            p[3] += __shfl_xor(p[3], m);
        }
        if (n_l == 0) {
            const int i = i0 + w * 4 + il;
            const int jb = j0 + kq * 4;
            float4 sv;
            float* pv = &sv.x;
#pragma unroll
            for (int reg = 0; reg < 4; ++reg) {
                int jg = jb + reg;
                float sc = p[reg] + bb3;
                sc = sc > 0.f ? sc : 0.f;
                if (jg == i || jg == 0) sc = 0.f;
                pv[reg] = sc;
            }
            *(float4*)(&score[((size_t)(b * 128 + i)) * 128 + jb]) = sv;
        }
    }
}

// ---------------- loss ----------------
__global__ __launch_bounds__(128) void k_loss1(
    const float* __restrict__ score, const int* __restrict__ tree, float* __restrict__ res)
{
    int k = blockIdx.x;
    int b = blockIdx.y;
    int head = tree[((size_t)b * 128 + k + 1) * 2 + 0];
    int dep  = tree[((size_t)b * 128 + k + 1) * 2 + 1];
    int i = threadIdx.x;
    float s = score[((size_t)b * 128 + i) * 128 + dep];
    float v = (i == dep) ? 0.f : __expf(s);
    __shared__ float redu[2];
#pragma unroll
    for (int off = 32; off >= 1; off >>= 1) v += __shfl_down(v, off, 64);
    if ((i & 63) == 0) redu[i >> 6] = v;
    __syncthreads();
    if (i == 0) {
        float norm = redu[0] + redu[1];
        float num = score[((size_t)b * 128 + head) * 128 + dep];
        res[b * 127 + k] = __logf(norm) - num;
    }
}

__global__ __launch_bounds__(256) void k_loss2(const float* __restrict__ res, float* __restrict__ out) {
    int tid = threadIdx.x;
    float a = 0.f;
    for (int idx = tid; idx < 16 * 127; idx += 256) a += res[idx];
    __shared__ float sm[256];
    sm[tid] = a;
    __syncthreads();
    for (int off = 128; off >= 1; off >>= 1) {
        if (tid < off) sm[tid] += sm[tid + off];
        __syncthreads();
    }
    if (tid == 0) out[0] = sm[0] / 127.f;
}

// ---------------- host launcher ----------------
extern "C" void kernel_launch(void* const* d_in, const int* in_sizes, int n_in,
                              void* d_out, int out_size, void* d_ws, size_t ws_size,
                              hipStream_t stream) {
    (void)in_sizes; (void)n_in; (void)out_size; (void)ws_size;
    const float* X    = (const float*)d_in[0];
    const float* Wih0 = (const float*)d_in[1];
    const float* Whh0 = (const float*)d_in[2];
    const float* bih0 = (const float*)d_in[3];
    const float* bhh0 = (const float*)d_in[4];
    const float* Wih1 = (const float*)d_in[5];
    const float* Whh1 = (const float*)d_in[6];
    const float* bih1 = (const float*)d_in[7];
    const float* bhh1 = (const float*)d_in[8];
    const float* W1   = (const float*)d_in[9];
    const float* b1   = (const float*)d_in[10];
    const float* W2   = (const float*)d_in[11];
    const float* b2   = (const float*)d_in[12];
    const float* W3   = (const float*)d_in[13];
    const float* b3   = (const float*)d_in[14];
    const int*   tree = (const int*)d_in[15];
    float* out = (float*)d_out;   // [0]=loss, [1..]=score

    float* ws = (float*)d_ws;
    size_t o = 0;
    float* WihT0 = ws + o; o += (size_t)2 * 200 * 1024;
    float* bsum0 = ws + o; o += 2048;
    float* bsum1 = ws + o; o += 2048;
    float* bhab  = ws + o; o += 512;
    unsigned char* Wf0 = (unsigned char*)(ws + o); o += (size_t)2 * 16 * 16384 / 4;
    unsigned char* Wf1 = (unsigned char*)(ws + o); o += (size_t)2 * 16 * 16384 / 4;
    unsigned short* w2f   = (unsigned short*)(ws + o); o += (size_t)4096 * 8 / 2;
    unsigned short* wfIh1 = (unsigned short*)(ws + o); o += (size_t)131072 * 8 / 2;
    unsigned short* wfW1  = (unsigned short*)(ws + o); o += (size_t)32768 * 8 / 2;
    float* xg   = ws + o; o += (size_t)2 * 2048 * 1024;
    float* xgf  = ws + o; o += (size_t)2 * 2048 * 1024;
    unsigned short* embt0 = (unsigned short*)(ws + o); o += (size_t)128 * 512 * 16 / 2;
    unsigned short* embt1 = (unsigned short*)(ws + o); o += (size_t)128 * 512 * 16 / 2;
    unsigned short* embR  = (unsigned short*)(ws + o); o += (size_t)2048 * 512 / 2;
    float* HaHb = ws + o; o += (size_t)2048 * 512;
    float* res  = ws + o; o += 2048;

    // prep
    k_transpose_N1024<<<dim3(800, 1, 2), 256, 0, stream>>>(Wih0, WihT0, 200);
    k_wfrag8<<<256, 256, 0, stream>>>(Whh0, Wf0);
    k_wfrag8<<<256, 256, 0, stream>>>(Whh1, Wf1);
    k_w2frag<<<16, 256, 0, stream>>>(W2, w2f);
    k_wfragb_ih1<<<512, 256, 0, stream>>>(Wih1, wfIh1);
    k_wfragb_w1<<<128, 256, 0, stream>>>(W1, wfW1);
    k_bias<<<18, 256, 0, stream>>>(bih0, bhh0, bih1, bhh1, b1, bsum0, bsum1, bhab);

    // layer 0
    k_gemm<<<dim3(4, 128, 2), 256, 0, stream>>>(X, WihT0, bsum0, xg, 2048, 200, 1024);
    k_reorder<<<4096, 256, 0, stream>>>(xg, xgf);
    k_lstm_mfma<<<2, 512, 0, stream>>>(xgf, Wf0, embt0);
    // layer 1 (MFMA GEMM via row-major bf16 emb)
    k_embR<<<128, 256, 0, stream>>>(embt0, embR);
    k_mgemm<<<dim3(4, 32, 2), 256, 0, stream>>>(embR, wfIh1, bsum1, xg, 1024);
    k_reorder<<<4096, 256, 0, stream>>>(xg, xgf);
    k_lstm_mfma<<<2, 512, 0, stream>>>(xgf, Wf1, embt1);
    // Ha|Hb (MFMA GEMM)
    k_embR<<<128, 256, 0, stream>>>(embt1, embR);
    k_mgemm<<<dim3(2, 32, 1), 256, 0, stream>>>(embR, wfW1, bhab, HaHb, 512);
    // scorer -> out+1
    k_scorer_mfma<<<dim3(8, 8, 16), 256, 0, stream>>>(HaHb, w2f, b2, W3, b3, out + 1);
    // loss
    k_loss1<<<dim3(127, 16), 128, 0, stream>>>(out + 1, tree, res);
    k_loss2<<<1, 256, 0, stream>>>(res, out);
}

// Round 17
// 657.171 us; speedup vs baseline: 1.3948x; 1.0347x over previous
//
#include <hip/hip_runtime.h>
#include <hip/hip_bf16.h>
#include <cstdint>
#include <cstddef>

// B=16, S=128, IN=200, H=256, 4H=1024, 2H=512

typedef __attribute__((ext_vector_type(8))) short bf16x8;
typedef __attribute__((ext_vector_type(4))) float f32x4;
typedef __attribute__((ext_vector_type(4))) unsigned short u16x4;

__device__ __forceinline__ float bf2f(unsigned short u) {
    return __uint_as_float(((unsigned)u) << 16);
}
__device__ __forceinline__ unsigned short f2bf(float f) {
    unsigned u = __float_as_uint(f);
    u = (u + 0x7FFFu + ((u >> 16) & 1u)) >> 16;
    return (unsigned short)u;
}

// float -> OCP e4m3fn with RNE (prep only)
__device__ __forceinline__ unsigned f2e4m3(float f) {
    unsigned u = __float_as_uint(f);
    unsigned s = (u >> 24) & 0x80u;
    int expf_ = (int)((u >> 23) & 0xFF);
    if (expf_ == 0) return s;
    int exp = expf_ - 127;
    if (exp < -10) return s;
    unsigned M = (u & 0x7FFFFF) | 0x800000;
    int e8 = exp + 7;
    int shift = 20;
    if (e8 < 1) { shift = 21 - e8; e8 = 0; }
    unsigned q = M >> shift;
    unsigned rem = M & ((1u << shift) - 1u);
    unsigned half = 1u << (shift - 1);
    if (rem > half || (rem == half && (q & 1))) q++;
    if (q >= 16) { q >>= 1; e8++; }
    if (e8 == 0 && (q & 8)) e8 = 1;
    if (e8 >= 16 || (e8 == 15 && (q & 7) == 7)) return s | 0x7Eu;
    return s | ((unsigned)e8 << 4) | (q & 7u);
}

// ---------------- prep kernels ----------------

// Whh -> fp8 A-fragments of 64*Whh, k-perm cOf(e)=(e&1)*4+(e>>1)  (R11 layout)
__global__ void k_wfrag8(const float* __restrict__ Whh, unsigned char* __restrict__ Wfrag8) {
    int idx = blockIdx.x * 256 + threadIdx.x;   // 65536 total
    int l = idx & 63;
    int t = (idx >> 6) & 3;
    int ks = (idx >> 8) & 7;
    int w = (idx >> 11) & 15;
    int d = idx >> 15;
    int r = l & 15;
    int kbase = ks * 32 + (l >> 4) * 8;
    int row = (r & 3) * 256 + w * 16 + t * 4 + (r >> 2);
    const float* src = Whh + (size_t)d * (1024 * 256) + (size_t)row * 256 + kbase;
    unsigned char* dst = Wfrag8 + (size_t)idx * 8;
#pragma unroll
    for (int e = 0; e < 8; ++e) {
        int c = (e & 1) * 4 + (e >> 1);
        dst[e] = (unsigned char)f2e4m3(64.f * src[c]);
    }
}

// W2 (128,256) fp32 -> B-fragment layout bf16 (scorer)
__global__ void k_w2frag(const float* __restrict__ W2, unsigned short* __restrict__ w2f) {
    int idx = blockIdx.x * 256 + threadIdx.x;   // 4096 total
    if (idx >= 4096) return;
    int l = idx & 63;
    int ks = (idx >> 6) & 7;
    int nt = idx >> 9;
    const float* src = W2 + (size_t)(nt * 16 + (l & 15)) * 256 + ks * 32 + (l >> 4) * 8;
    unsigned short* dst = w2f + (size_t)idx * 8;
#pragma unroll
    for (int e = 0; e < 8; ++e) dst[e] = f2bf(src[e]);
}

// Generic mgemm B-frags: W (z,Nrows,Kin) row-major -> wf[((z*KSN+ks)*NT+nt)*64+l][e]
// = bf16(W[z][nt*16+(l&15)][ks*32+(l>>4)*8+e]) (zero-padded past Kin).
// grid-stride over z*KSN*NT*64 entries.
__global__ void k_wfragb(const float* __restrict__ W, unsigned short* __restrict__ wf,
                         int KSN, int NT, int Kin, int total) {
    int o = blockIdx.x * 256 + threadIdx.x;
    if (o >= total) return;
    int l = o & 63;
    int nt = (o >> 6) % NT;
    int rest = (o >> 6) / NT;
    int ks = rest % KSN;
    int z = rest / KSN;
    int n = nt * 16 + (l & 15);
    int k0 = ks * 32 + (l >> 4) * 8;
    const float* src = W + ((size_t)z * (NT * 16) + n) * Kin;
    unsigned short* dst = wf + (size_t)o * 8;
#pragma unroll
    for (int e = 0; e < 8; ++e) {
        int k = k0 + e;
        dst[e] = (k < Kin) ? f2bf(src[k]) : (unsigned short)0;
    }
}

// W1 (256,1024) -> mgemm B-frags bf16 for Ha|Hb (N=512, K=512):
__global__ void k_wfragb_w1(const float* __restrict__ W1, unsigned short* __restrict__ wf) {
    int o = blockIdx.x * 256 + threadIdx.x;   // 32768 total
    int l = o & 63;
    int nt = (o >> 6) & 31;
    int ks = o >> 11;
    int oc = nt * 16 + (l & 15);
    int k0 = ks * 32 + (l >> 4) * 8;
    unsigned short* dst = wf + (size_t)o * 8;
#pragma unroll
    for (int e = 0; e < 8; ++e) {
        int k = k0 + e;
        float v = (oc < 256) ? W1[(size_t)oc * 1024 + k] : W1[(size_t)(oc - 256) * 1024 + 512 + k];
        dst[e] = f2bf(v);
    }
}

// X (16,128,200) fp32 -> Xb [2048][224] bf16 zero-padded
__global__ __launch_bounds__(256) void k_xbf16(const float* __restrict__ X, unsigned short* __restrict__ Xb) {
    int idx = blockIdx.x * 256 + threadIdx.x;   // 2048*224 = 458752
    if (idx >= 2048 * 224) return;
    int m = idx / 224;
    int k = idx - m * 224;
    Xb[idx] = (k < 200) ? f2bf(X[(size_t)m * 200 + k]) : (unsigned short)0;
}

__global__ void k_bias(const float* __restrict__ bih0, const float* __restrict__ bhh0,
                       const float* __restrict__ bih1, const float* __restrict__ bhh1,
                       const float* __restrict__ b1,
                       float* __restrict__ bsum0, float* __restrict__ bsum1, float* __restrict__ bhab) {
    int idx = blockIdx.x * 256 + threadIdx.x;
    if (idx < 2048) bsum0[idx] = bih0[idx] + bhh0[idx];
    else if (idx < 4096) { int i = idx - 2048; bsum1[i] = bih1[i] + bhh1[i]; }
    else if (idx < 4608) { int i = idx - 4096; bhab[i] = (i < 256) ? b1[i] : 0.f; }
}

// xg -> xgfrag, PRE-SCALED by 64
__global__ __launch_bounds__(256) void k_reorder(const float* __restrict__ xg, float* __restrict__ xgf) {
    int idx = blockIdx.x * 256 + threadIdx.x;   // 1048576 total
    int n4 = idx & 255;
    int m = (idx >> 8) & 2047;
    int d = idx >> 19;
    int n0 = n4 * 4;
    int q = n0 >> 8;
    int jbase = n0 & 255;
    int b = m >> 7, t = m & 127;
    float4 v = *(const float4*)(xg + ((size_t)(d * 2048 + m)) * 1024 + n0);
    float* base = xgf + (size_t)d * 2097152;
    float vv[4] = {v.x * 64.f, v.y * 64.f, v.z * 64.f, v.w * 64.f};
#pragma unroll
    for (int dj = 0; dj < 4; ++dj) {
        int j = jbase + dj;
        int fi = (t * 4096 + (j >> 4) * 256 + ((j >> 2) & 3) * 64 + dj * 16 + b) * 4 + q;
        base[fi] = vv[dj];
    }
}

// embt [t][j][b] -> embR [m=b*128+t][j] row-major bf16
__global__ __launch_bounds__(256) void k_embR(const unsigned short* __restrict__ embt,
                                              unsigned short* __restrict__ embR) {
    int t = blockIdx.x;
    for (int j = threadIdx.x; j < 512; j += 256) {
        uint4 v = *(const uint4*)(embt + (size_t)t * 8192 + j * 16);
        const unsigned short* pv = (const unsigned short*)&v;
#pragma unroll
        for (int b = 0; b < 16; ++b)
            embR[((size_t)(b * 128 + t)) * 512 + j] = pv[b];
    }
}

// ---------------- MFMA GEMM (template K): out[z][m][n] = bias + A[m][:].wf --
// M=2048. grid (N/256, 32, z), 256 thr (4 waves). A row-major bf16 stride K.
template<int K>
__global__ __launch_bounds__(256) void k_mgemm(
    const unsigned short* __restrict__ A,    // [2048][K] bf16
    const unsigned short* __restrict__ wf,   // [z][K/32][N/16][64][8] bf16
    const float* __restrict__ bias,          // [z][N]
    float* __restrict__ out,                 // [z][2048][N]
    int N)
{
    constexpr int KSN = K / 32;
    constexpr int K8 = K / 8;
    constexpr int LDA = K + 8;
    const int z = blockIdx.z;
    const int NT = N >> 4;
    const int tid = threadIdx.x;
    const int w = tid >> 6;
    const int l = tid & 63;
    const int arow = l & 15;
    const int kq = l >> 4;
    const int mbase = blockIdx.y * 64;
    const int ntb = blockIdx.x * 16 + w * 4;

    __shared__ __align__(16) unsigned short As[64 * LDA];

    for (int i = tid; i < 64 * K8; i += 256) {
        int r = i / K8, k8 = i - r * K8;
        *(bf16x8*)(&As[r * LDA + k8 * 8]) =
            *(const bf16x8*)(A + (size_t)(mbase + r) * K + k8 * 8);
    }

    const bf16x8* wb = (const bf16x8*)wf + (size_t)z * KSN * NT * 64;
    bf16x8 bf[4], bfn[4];
#pragma unroll
    for (int ntl = 0; ntl < 4; ++ntl) bf[ntl] = wb[(size_t)(0 * NT + ntb + ntl) * 64 + l];

    f32x4 acc[4][4];
#pragma unroll
    for (int ntl = 0; ntl < 4; ++ntl) {
        float bv = bias[(size_t)z * N + (ntb + ntl) * 16 + arow];
#pragma unroll
        for (int mt = 0; mt < 4; ++mt) acc[mt][ntl] = f32x4{bv, bv, bv, bv};
    }
    __syncthreads();

#pragma unroll
    for (int ks = 0; ks < KSN; ++ks) {
        if (ks < KSN - 1) {
#pragma unroll
            for (int ntl = 0; ntl < 4; ++ntl)
                bfn[ntl] = wb[(size_t)((ks + 1) * NT + ntb + ntl) * 64 + l];
        }
        bf16x8 af[4];
#pragma unroll
        for (int mt = 0; mt < 4; ++mt)
            af[mt] = *(const bf16x8*)(&As[(mt * 16 + arow) * LDA + ks * 32 + kq * 8]);
#pragma unroll
        for (int mt = 0; mt < 4; ++mt)
#pragma unroll
            for (int ntl = 0; ntl < 4; ++ntl)
                acc[mt][ntl] = __builtin_amdgcn_mfma_f32_16x16x32_bf16(af[mt], bf[ntl], acc[mt][ntl], 0, 0, 0);
#pragma unroll
        for (int ntl = 0; ntl < 4; ++ntl) bf[ntl] = bfn[ntl];
    }

    float* oz = out + (size_t)z * 2048 * N;
#pragma unroll
    for (int mt = 0; mt < 4; ++mt)
#pragma unroll
        for (int ntl = 0; ntl < 4; ++ntl) {
            int ncol = (ntb + ntl) * 16 + arow;
#pragma unroll
            for (int reg = 0; reg < 4; ++reg) {
                int m = mbase + mt * 16 + kq * 4 + reg;
                oz[(size_t)m * N + ncol] = acc[mt][ntl][reg];
            }
        }
}

// ---------------- MFMA LSTM recurrence (R11 exact, measured-best 252us) ----
#define GATE8(A, C, H) { \
    float gi = A[0] * 0.015625f, gf = A[1] * 0.015625f, gg = A[2] * 0.015625f, go = A[3] * 0.015625f; \
    float si = __builtin_amdgcn_rcpf(1.f + __expf(-gi)); \
    float sf = __builtin_amdgcn_rcpf(1.f + __expf(-gf)); \
    float so = __builtin_amdgcn_rcpf(1.f + __expf(-go)); \
    float eg = __expf(2.f * gg); \
    float tg = 1.f - 2.f * __builtin_amdgcn_rcpf(eg + 1.f); \
    C = sf * C + si * tg; \
    float ec = __expf(2.f * C); \
    float tc = 1.f - 2.f * __builtin_amdgcn_rcpf(ec + 1.f); \
    H = so * tc; }

__global__ __launch_bounds__(512, 2) void k_lstm_mfma(
    const float* __restrict__ xgf,            // [2][128][16][4][64][4], pre-scaled x64
    const unsigned char* __restrict__ Wfrag8, // [2][16][8][4][64][8] fp8 of 64*Whh (k-perm)
    unsigned short* __restrict__ embt)        // [128][512][16] bf16 ([t][j][b])
{
    const int d = blockIdx.x;
    const int tid = threadIdx.x;
    const int wv = tid >> 6;      // 0..7
    const int l = tid & 63;
    const int b = l & 15;
    const int jh = l >> 4;
    const int s0 = wv * 2, s1 = wv * 2 + 1;

    __shared__ __align__(8) unsigned char hB[4096];   // fp8 h, single buffer

    const unsigned char* wg0 = Wfrag8 + ((size_t)(d * 16 + s0)) * 16384;
    const unsigned char* wg1 = Wfrag8 + ((size_t)(d * 16 + s1)) * 16384;
    long W0[8][4], W1[8][4];
#pragma unroll
    for (int ks = 0; ks < 8; ++ks)
#pragma unroll
        for (int t4 = 0; t4 < 4; ++t4) {
            W0[ks][t4] = *(const long*)(wg0 + ((size_t)((ks * 4 + t4) * 64 + l)) * 8);
            W1[ks][t4] = *(const long*)(wg1 + ((size_t)((ks * 4 + t4) * 64 + l)) * 8);
        }
#pragma unroll
    for (int ks = 0; ks < 8; ++ks)
#pragma unroll
        for (int t4 = 0; t4 < 4; ++t4) {
            asm volatile("" : "+v"(W0[ks][t4]));
            asm volatile("" : "+v"(W1[ks][t4]));
        }

    ((uint64_t*)hB)[tid] = 0ull;

    const int sgn = d ? -1 : 1;
    int t = d ? 127 : 0;
    const f32x4* xb = (const f32x4*)(xgf) + (size_t)d * 524288;
    const int xo0 = s0 * 256 + l;
    const int xo1 = s1 * 256 + l;

    f32x4 a0 = xb[t * 4096 + xo0];
    f32x4 a1 = xb[t * 4096 + xo0 + 64];
    f32x4 a2 = xb[t * 4096 + xo0 + 128];
    f32x4 a3 = xb[t * 4096 + xo0 + 192];
    f32x4 e0 = xb[t * 4096 + xo1];
    f32x4 e1 = xb[t * 4096 + xo1 + 64];
    f32x4 e2 = xb[t * 4096 + xo1 + 128];
    f32x4 e3 = xb[t * 4096 + xo1 + 192];

    float c0 = 0.f, c1 = 0.f, c2 = 0.f, c3 = 0.f;
    float c4 = 0.f, c5 = 0.f, c6 = 0.f, c7 = 0.f;
    const int hrd = jh * 128 + b * 8;
    unsigned short* ep0 = embt + (size_t)d * 4096 + (size_t)s0 * 256 + l;
    unsigned short* ep1 = embt + (size_t)d * 4096 + (size_t)s1 * 256 + l;
    unsigned char* hw0 = hB + s0 * 256 + b * 8 + jh * 2;
    unsigned char* hw1 = hB + s1 * 256 + b * 8 + jh * 2;
    __syncthreads();

    for (int s = 0; s < 128; ++s) {
#pragma unroll
        for (int ks = 0; ks < 8; ++ks) {
            long hf = *(const long*)(hB + ks * 512 + hrd);
            a0 = __builtin_amdgcn_mfma_f32_16x16x32_fp8_fp8(W0[ks][0], hf, a0, 0, 0, 0);
            a1 = __builtin_amdgcn_mfma_f32_16x16x32_fp8_fp8(W0[ks][1], hf, a1, 0, 0, 0);
            a2 = __builtin_amdgcn_mfma_f32_16x16x32_fp8_fp8(W0[ks][2], hf, a2, 0, 0, 0);
            a3 = __builtin_amdgcn_mfma_f32_16x16x32_fp8_fp8(W0[ks][3], hf, a3, 0, 0, 0);
            e0 = __builtin_amdgcn_mfma_f32_16x16x32_fp8_fp8(W1[ks][0], hf, e0, 0, 0, 0);
            e1 = __builtin_amdgcn_mfma_f32_16x16x32_fp8_fp8(W1[ks][1], hf, e1, 0, 0, 0);
            e2 = __builtin_amdgcn_mfma_f32_16x16x32_fp8_fp8(W1[ks][2], hf, e2, 0, 0, 0);
            e3 = __builtin_amdgcn_mfma_f32_16x16x32_fp8_fp8(W1[ks][3], hf, e3, 0, 0, 0);
        }

        float h0, h1, h2, h3, h4, h5, h6, h7;
        GATE8(a0, c0, h0);
        GATE8(a1, c1, h1);
        GATE8(a2, c2, h2);
        GATE8(a3, c3, h3);
        GATE8(e0, c4, h4);
        GATE8(e1, c5, h5);
        GATE8(e2, c6, h6);
        GATE8(e3, c7, h7);

        unsigned r01, r23, r45, r67;
        asm("v_cvt_pk_bf16_f32 %0, %1, %2" : "=v"(r01) : "v"(h0), "v"(h1));
        asm("v_cvt_pk_bf16_f32 %0, %1, %2" : "=v"(r23) : "v"(h2), "v"(h3));
        asm("v_cvt_pk_bf16_f32 %0, %1, %2" : "=v"(r45) : "v"(h4), "v"(h5));
        asm("v_cvt_pk_bf16_f32 %0, %1, %2" : "=v"(r67) : "v"(h6), "v"(h7));
        {
            unsigned short* p0 = ep0 + (size_t)t * 8192;
            p0[0]   = (unsigned short)r01;
            p0[64]  = (unsigned short)(r01 >> 16);
            p0[128] = (unsigned short)r23;
            p0[192] = (unsigned short)(r23 >> 16);
            unsigned short* p1 = ep1 + (size_t)t * 8192;
            p1[0]   = (unsigned short)r45;
            p1[64]  = (unsigned short)(r45 >> 16);
            p1[128] = (unsigned short)r67;
            p1[192] = (unsigned short)(r67 >> 16);
        }

        unsigned q01 = __builtin_amdgcn_cvt_pk_fp8_f32(h0, h1, 0, false);
        unsigned q23 = __builtin_amdgcn_cvt_pk_fp8_f32(h2, h3, 0, false);
        unsigned q45 = __builtin_amdgcn_cvt_pk_fp8_f32(h4, h5, 0, false);
        unsigned q67 = __builtin_amdgcn_cvt_pk_fp8_f32(h6, h7, 0, false);

        int tn = (s == 127) ? t : (t + sgn);
        a0 = xb[tn * 4096 + xo0];
        a1 = xb[tn * 4096 + xo0 + 64];
        a2 = xb[tn * 4096 + xo0 + 128];
        a3 = xb[tn * 4096 + xo0 + 192];
        e0 = xb[tn * 4096 + xo1];
        e1 = xb[tn * 4096 + xo1 + 64];
        e2 = xb[tn * 4096 + xo1 + 128];
        e3 = xb[tn * 4096 + xo1 + 192];
        __syncthreads();
        *(unsigned short*)(hw0)       = (unsigned short)q01;
        *(unsigned short*)(hw0 + 128) = (unsigned short)q23;
        *(unsigned short*)(hw1)       = (unsigned short)q45;
        *(unsigned short*)(hw1 + 128) = (unsigned short)q67;
        __syncthreads();
        t = tn;
    }
}

// ---------------- MFMA pairwise scorer (R7 winner, unchanged) ----------------
__global__ __launch_bounds__(256, 2) void k_scorer_mfma(
    const float* __restrict__ HaHb, const unsigned short* __restrict__ w2f,
    const float* __restrict__ b2, const float* __restrict__ W3,
    const float* __restrict__ b3v, float* __restrict__ score)
{
    const int jt = blockIdx.x, it = blockIdx.y, b = blockIdx.z;
    const int j0 = jt * 16, i0 = it * 16;
    const int tid = threadIdx.x;
    const int w = tid >> 6;
    const int l = tid & 63;
    const int n_l = l & 15;
    const int kq = l >> 4;

    __shared__ __align__(16) unsigned short HaS[16 * 264];
    __shared__ __align__(16) unsigned short HbS[16 * 264];

    {
        const float* base = HaHb + ((size_t)(b * 128)) * 512;
        int rr = tid >> 4;
        int q = tid & 15;
#pragma unroll
        for (int rep = 0; rep < 4; ++rep) {
            int k0 = q * 4 + rep * 64;
            float4 va = *(const float4*)(base + (size_t)(i0 + rr) * 512 + k0);
            float4 vb = *(const float4*)(base + (size_t)(j0 + rr) * 512 + 256 + k0);
            u16x4 ua = { f2bf(va.x), f2bf(va.y), f2bf(va.z), f2bf(va.w) };
            u16x4 ub = { f2bf(vb.x), f2bf(vb.y), f2bf(vb.z), f2bf(vb.w) };
            *(u16x4*)(&HaS[rr * 264 + k0]) = ua;
            *(u16x4*)(&HbS[rr * 264 + k0]) = ub;
        }
    }

    float b2v[8], w3v[8];
#pragma unroll
    for (int nt = 0; nt < 8; ++nt) {
        b2v[nt] = b2[nt * 16 + n_l];
        w3v[nt] = W3[nt * 16 + n_l];
    }

    f32x4 acc[4][8];
#pragma unroll
    for (int il = 0; il < 4; ++il)
#pragma unroll
        for (int nt = 0; nt < 8; ++nt) acc[il][nt] = f32x4{0.f, 0.f, 0.f, 0.f};

    const bf16x8* wbase = (const bf16x8*)w2f;
    bf16x8 wf[8], wfn[8];
#pragma unroll
    for (int nt = 0; nt < 8; ++nt) wf[nt] = wbase[(nt * 8 + 0) * 64 + l];

    __syncthreads();

#pragma unroll
    for (int ks = 0; ks < 8; ++ks) {
        if (ks < 7) {
#pragma unroll
            for (int nt = 0; nt < 8; ++nt) wfn[nt] = wbase[(nt * 8 + ks + 1) * 64 + l];
        }
#pragma unroll
        for (int il = 0; il < 4; ++il) {
            const int irow = w * 4 + il;
            bf16x8 ha = *(const bf16x8*)(&HaS[irow * 264 + ks * 32 + kq * 8]);
            bf16x8 hb = *(const bf16x8*)(&HbS[n_l * 264 + ks * 32 + kq * 8]);
            bf16x8 av;
#pragma unroll
            for (int e = 0; e < 8; ++e) {
                float v = bf2f((unsigned short)ha[e]) + bf2f((unsigned short)hb[e]);
                v = v > 0.f ? v : 0.f;
                av[e] = (short)f2bf(v);
            }
#pragma unroll
            for (int nt = 0; nt < 8; ++nt)
                acc[il][nt] = __builtin_amdgcn_mfma_f32_16x16x32_bf16(av, wf[nt], acc[il][nt], 0, 0, 0);
        }
#pragma unroll
        for (int nt = 0; nt < 8; ++nt) wf[nt] = wfn[nt];
    }

    const float bb3 = b3v[0];
#pragma unroll
    for (int il = 0; il < 4; ++il) {
        float p[4];
#pragma unroll
        for (int reg = 0; reg < 4; ++reg) {
            float v = 0.f;
#pragma unroll
            for (int nt = 0; nt < 8; ++nt) {
                float h2v = acc[il][nt][reg] + b2v[nt];
                h2v = h2v > 0.f ? h2v : 0.f;
                v += h2v * w3v[nt];
            }
            p[reg] = v;
        }
#pragma unroll
        for (int m = 1; m < 16; m <<= 1) {
            p[0] += __shfl_xor(p[0], m);
            p[1] += __shfl_xor(p[1], m);
            p[2] += __shfl_xor(p[2], m);
            p[3] += __shfl_xor(p[3], m);
        }
        if (n_l == 0) {
            const int i = i0 + w * 4 + il;
            const int jb = j0 + kq * 4;
            float4 sv;
            float* pv = &sv.x;
#pragma unroll
            for (int reg = 0; reg < 4; ++reg) {
                int jg = jb + reg;
                float sc = p[reg] + bb3;
                sc = sc > 0.f ? sc : 0.f;
                if (jg == i || jg == 0) sc = 0.f;
                pv[reg] = sc;
            }
            *(float4*)(&score[((size_t)(b * 128 + i)) * 128 + jb]) = sv;
        }
    }
}

// ---------------- loss ----------------
__global__ __launch_bounds__(128) void k_loss1(
    const float* __restrict__ score, const int* __restrict__ tree, float* __restrict__ res)
{
    int k = blockIdx.x;
    int b = blockIdx.y;
    int head = tree[((size_t)b * 128 + k + 1) * 2 + 0];
    int dep  = tree[((size_t)b * 128 + k + 1) * 2 + 1];
    int i = threadIdx.x;
    float s = score[((size_t)b * 128 + i) * 128 + dep];
    float v = (i == dep) ? 0.f : __expf(s);
    __shared__ float redu[2];
#pragma unroll
    for (int off = 32; off >= 1; off >>= 1) v += __shfl_down(v, off, 64);
    if ((i & 63) == 0) redu[i >> 6] = v;
    __syncthreads();
    if (i == 0) {
        float norm = redu[0] + redu[1];
        float num = score[((size_t)b * 128 + head) * 128 + dep];
        res[b * 127 + k] = __logf(norm) - num;
    }
}

__global__ __launch_bounds__(256) void k_loss2(const float* __restrict__ res, float* __restrict__ out) {
    int tid = threadIdx.x;
    float a = 0.f;
    for (int idx = tid; idx < 16 * 127; idx += 256) a += res[idx];
    __shared__ float sm[256];
    sm[tid] = a;
    __syncthreads();
    for (int off = 128; off >= 1; off >>= 1) {
        if (tid < off) sm[tid] += sm[tid + off];
        __syncthreads();
    }
    if (tid == 0) out[0] = sm[0] / 127.f;
}

// ---------------- host launcher ----------------
extern "C" void kernel_launch(void* const* d_in, const int* in_sizes, int n_in,
                              void* d_out, int out_size, void* d_ws, size_t ws_size,
                              hipStream_t stream) {
    (void)in_sizes; (void)n_in; (void)out_size; (void)ws_size;
    const float* X    = (const float*)d_in[0];
    const float* Wih0 = (const float*)d_in[1];
    const float* Whh0 = (const float*)d_in[2];
    const float* bih0 = (const float*)d_in[3];
    const float* bhh0 = (const float*)d_in[4];
    const float* Wih1 = (const float*)d_in[5];
    const float* Whh1 = (const float*)d_in[6];
    const float* bih1 = (const float*)d_in[7];
    const float* bhh1 = (const float*)d_in[8];
    const float* W1   = (const float*)d_in[9];
    const float* b1   = (const float*)d_in[10];
    const float* W2   = (const float*)d_in[11];
    const float* b2   = (const float*)d_in[12];
    const float* W3   = (const float*)d_in[13];
    const float* b3   = (const float*)d_in[14];
    const int*   tree = (const int*)d_in[15];
    float* out = (float*)d_out;   // [0]=loss, [1..]=score

    float* ws = (float*)d_ws;
    size_t o = 0;
    float* bsum0 = ws + o; o += 2048;
    float* bsum1 = ws + o; o += 2048;
    float* bhab  = ws + o; o += 512;
    unsigned char* Wf0 = (unsigned char*)(ws + o); o += (size_t)2 * 16 * 16384 / 4;
    unsigned char* Wf1 = (unsigned char*)(ws + o); o += (size_t)2 * 16 * 16384 / 4;
    unsigned short* w2f   = (unsigned short*)(ws + o); o += (size_t)4096 * 8 / 2;
    unsigned short* wfIh0 = (unsigned short*)(ws + o); o += (size_t)2 * 7 * 64 * 64 * 8 / 2;
    unsigned short* wfIh1 = (unsigned short*)(ws + o); o += (size_t)2 * 16 * 64 * 64 * 8 / 2;
    unsigned short* wfW1  = (unsigned short*)(ws + o); o += (size_t)16 * 32 * 64 * 8 / 2;
    unsigned short* Xb    = (unsigned short*)(ws + o); o += (size_t)2048 * 224 / 2;
    float* xg   = ws + o; o += (size_t)2 * 2048 * 1024;
    float* xgf  = ws + o; o += (size_t)2 * 2048 * 1024;
    unsigned short* embt0 = (unsigned short*)(ws + o); o += (size_t)128 * 512 * 16 / 2;
    unsigned short* embt1 = (unsigned short*)(ws + o); o += (size_t)128 * 512 * 16 / 2;
    unsigned short* embR  = (unsigned short*)(ws + o); o += (size_t)2048 * 512 / 2;
    float* HaHb = ws + o; o += (size_t)2048 * 512;
    float* res  = ws + o; o += 2048;

    // prep
    k_wfrag8<<<256, 256, 0, stream>>>(Whh0, Wf0);
    k_wfrag8<<<256, 256, 0, stream>>>(Whh1, Wf1);
    k_w2frag<<<16, 256, 0, stream>>>(W2, w2f);
    k_wfragb<<<224, 256, 0, stream>>>(Wih0, wfIh0, 7, 64, 200, 2 * 7 * 64 * 64);
    k_wfragb<<<512, 256, 0, stream>>>(Wih1, wfIh1, 16, 64, 512, 2 * 16 * 64 * 64);
    k_wfragb_w1<<<128, 256, 0, stream>>>(W1, wfW1);
    k_xbf16<<<1792, 256, 0, stream>>>(X, Xb);
    k_bias<<<18, 256, 0, stream>>>(bih0, bhh0, bih1, bhh1, b1, bsum0, bsum1, bhab);

    // layer 0 (MFMA GEMM, K=224 zero-padded)
    k_mgemm<224><<<dim3(4, 32, 2), 256, 0, stream>>>(Xb, wfIh0, bsum0, xg, 1024);
    k_reorder<<<4096, 256, 0, stream>>>(xg, xgf);
    k_lstm_mfma<<<2, 512, 0, stream>>>(xgf, Wf0, embt0);
    // layer 1 (MFMA GEMM, K=512)
    k_embR<<<128, 256, 0, stream>>>(embt0, embR);
    k_mgemm<512><<<dim3(4, 32, 2), 256, 0, stream>>>(embR, wfIh1, bsum1, xg, 1024);
    k_reorder<<<4096, 256, 0, stream>>>(xg, xgf);
    k_lstm_mfma<<<2, 512, 0, stream>>>(xgf, Wf1, embt1);
    // Ha|Hb (MFMA GEMM, K=512)
    k_embR<<<128, 256, 0, stream>>>(embt1, embR);
    k_mgemm<512><<<dim3(2, 32, 1), 256, 0, stream>>>(embR, wfW1, bhab, HaHb, 512);
    // scorer -> out+1
    k_scorer_mfma<<<dim3(8, 8, 16), 256, 0, stream>>>(HaHb, w2f, b2, W3, b3, out + 1);
    // loss
    k_loss1<<<dim3(127, 16), 128, 0, stream>>>(out + 1, tree, res);
    k_loss2<<<1, 256, 0, stream>>>(res, out);
}

// Round 18
// 654.033 us; speedup vs baseline: 1.4014x; 1.0048x over previous
//
#include <hip/hip_runtime.h>
#include <hip/hip_bf16.h>
#include <cstdint>
#include <cstddef>

// B=16, S=128, IN=200, H=256, 4H=1024, 2H=512

typedef __attribute__((ext_vector_type(8))) short bf16x8;
typedef __attribute__((ext_vector_type(4))) float f32x4;
typedef __attribute__((ext_vector_type(4))) unsigned short u16x4;

__device__ __forceinline__ float bf2f(unsigned short u) {
    return __uint_as_float(((unsigned)u) << 16);
}
__device__ __forceinline__ unsigned short f2bf(float f) {
    unsigned u = __float_as_uint(f);
    u = (u + 0x7FFFu + ((u >> 16) & 1u)) >> 16;
    return (unsigned short)u;
}

// float -> OCP e4m3fn with RNE (prep only)
__device__ __forceinline__ unsigned f2e4m3(float f) {
    unsigned u = __float_as_uint(f);
    unsigned s = (u >> 24) & 0x80u;
    int expf_ = (int)((u >> 23) & 0xFF);
    if (expf_ == 0) return s;
    int exp = expf_ - 127;
    if (exp < -10) return s;
    unsigned M = (u & 0x7FFFFF) | 0x800000;
    int e8 = exp + 7;
    int shift = 20;
    if (e8 < 1) { shift = 21 - e8; e8 = 0; }
    unsigned q = M >> shift;
    unsigned rem = M & ((1u << shift) - 1u);
    unsigned half = 1u << (shift - 1);
    if (rem > half || (rem == half && (q & 1))) q++;
    if (q >= 16) { q >>= 1; e8++; }
    if (e8 == 0 && (q & 8)) e8 = 1;
    if (e8 >= 16 || (e8 == 15 && (q & 7) == 7)) return s | 0x7Eu;
    return s | ((unsigned)e8 << 4) | (q & 7u);
}

// ---------------- prep kernels ----------------

// Whh -> fp8 A-fragments of 64*Whh, k-perm cOf(e)=(e&1)*4+(e>>1)  (R11 layout)
__global__ void k_wfrag8(const float* __restrict__ Whh, unsigned char* __restrict__ Wfrag8) {
    int idx = blockIdx.x * 256 + threadIdx.x;   // 65536 total
    int l = idx & 63;
    int t = (idx >> 6) & 3;
    int ks = (idx >> 8) & 7;
    int w = (idx >> 11) & 15;
    int d = idx >> 15;
    int r = l & 15;
    int kbase = ks * 32 + (l >> 4) * 8;
    int row = (r & 3) * 256 + w * 16 + t * 4 + (r >> 2);
    const float* src = Whh + (size_t)d * (1024 * 256) + (size_t)row * 256 + kbase;
    unsigned char* dst = Wfrag8 + (size_t)idx * 8;
#pragma unroll
    for (int e = 0; e < 8; ++e) {
        int c = (e & 1) * 4 + (e >> 1);
        dst[e] = (unsigned char)f2e4m3(64.f * src[c]);
    }
}

// W2 (128,256) fp32 -> B-fragment layout bf16 (scorer)
__global__ void k_w2frag(const float* __restrict__ W2, unsigned short* __restrict__ w2f) {
    int idx = blockIdx.x * 256 + threadIdx.x;   // 4096 total
    if (idx >= 4096) return;
    int l = idx & 63;
    int ks = (idx >> 6) & 7;
    int nt = idx >> 9;
    const float* src = W2 + (size_t)(nt * 16 + (l & 15)) * 256 + ks * 32 + (l >> 4) * 8;
    unsigned short* dst = w2f + (size_t)idx * 8;
#pragma unroll
    for (int e = 0; e < 8; ++e) dst[e] = f2bf(src[e]);
}

// Generic mgemm B-frags: W (z,Nrows,Kin) row-major -> wf[((z*KSN+ks)*NT+nt)*64+l][e]
__global__ void k_wfragb(const float* __restrict__ W, unsigned short* __restrict__ wf,
                         int KSN, int NT, int Kin, int total) {
    int o = blockIdx.x * 256 + threadIdx.x;
    if (o >= total) return;
    int l = o & 63;
    int nt = (o >> 6) % NT;
    int rest = (o >> 6) / NT;
    int ks = rest % KSN;
    int z = rest / KSN;
    int n = nt * 16 + (l & 15);
    int k0 = ks * 32 + (l >> 4) * 8;
    const float* src = W + ((size_t)z * (NT * 16) + n) * Kin;
    unsigned short* dst = wf + (size_t)o * 8;
#pragma unroll
    for (int e = 0; e < 8; ++e) {
        int k = k0 + e;
        dst[e] = (k < Kin) ? f2bf(src[k]) : (unsigned short)0;
    }
}

// W1 (256,1024) -> mgemm B-frags bf16 for Ha|Hb (N=512, K=512):
__global__ void k_wfragb_w1(const float* __restrict__ W1, unsigned short* __restrict__ wf) {
    int o = blockIdx.x * 256 + threadIdx.x;   // 32768 total
    int l = o & 63;
    int nt = (o >> 6) & 31;
    int ks = o >> 11;
    int oc = nt * 16 + (l & 15);
    int k0 = ks * 32 + (l >> 4) * 8;
    unsigned short* dst = wf + (size_t)o * 8;
#pragma unroll
    for (int e = 0; e < 8; ++e) {
        int k = k0 + e;
        float v = (oc < 256) ? W1[(size_t)oc * 1024 + k] : W1[(size_t)(oc - 256) * 1024 + 512 + k];
        dst[e] = f2bf(v);
    }
}

// X (16,128,200) fp32 -> Xb [2048][224] bf16 zero-padded
__global__ __launch_bounds__(256) void k_xbf16(const float* __restrict__ X, unsigned short* __restrict__ Xb) {
    int idx = blockIdx.x * 256 + threadIdx.x;   // 2048*224 = 458752
    if (idx >= 2048 * 224) return;
    int m = idx / 224;
    int k = idx - m * 224;
    Xb[idx] = (k < 200) ? f2bf(X[(size_t)m * 200 + k]) : (unsigned short)0;
}

__global__ void k_bias(const float* __restrict__ bih0, const float* __restrict__ bhh0,
                       const float* __restrict__ bih1, const float* __restrict__ bhh1,
                       const float* __restrict__ b1,
                       float* __restrict__ bsum0, float* __restrict__ bsum1, float* __restrict__ bhab) {
    int idx = blockIdx.x * 256 + threadIdx.x;
    if (idx < 2048) bsum0[idx] = bih0[idx] + bhh0[idx];
    else if (idx < 4096) { int i = idx - 2048; bsum1[i] = bih1[i] + bhh1[i]; }
    else if (idx < 4608) { int i = idx - 4096; bhab[i] = (i < 256) ? b1[i] : 0.f; }
}

// embt [t][j][b] -> embR [m=b*128+t][j] row-major bf16
__global__ __launch_bounds__(256) void k_embR(const unsigned short* __restrict__ embt,
                                              unsigned short* __restrict__ embR) {
    int t = blockIdx.x;
    for (int j = threadIdx.x; j < 512; j += 256) {
        uint4 v = *(const uint4*)(embt + (size_t)t * 8192 + j * 16);
        const unsigned short* pv = (const unsigned short*)&v;
#pragma unroll
        for (int b = 0; b < 16; ++b)
            embR[((size_t)(b * 128 + t)) * 512 + j] = pv[b];
    }
}

// ---------------- MFMA GEMM (template K, optional fused xgf epilogue) ------
// M=2048. grid (N/256, 32, z), 256 thr (4 waves). A row-major bf16 stride K.
// TO_XGF: write 64*(acc) directly into the xgf fragment layout (fused reorder).
template<int K, bool TO_XGF>
__global__ __launch_bounds__(256) void k_mgemm(
    const unsigned short* __restrict__ A,    // [2048][K] bf16
    const unsigned short* __restrict__ wf,   // [z][K/32][N/16][64][8] bf16
    const float* __restrict__ bias,          // [z][N]
    float* __restrict__ out,                 // TO_XGF ? xgf : [z][2048][N]
    int N)
{
    constexpr int KSN = K / 32;
    constexpr int K8 = K / 8;
    constexpr int LDA = K + 8;
    const int z = blockIdx.z;
    const int NT = N >> 4;
    const int tid = threadIdx.x;
    const int w = tid >> 6;
    const int l = tid & 63;
    const int arow = l & 15;
    const int kq = l >> 4;
    const int mbase = blockIdx.y * 64;
    const int ntb = blockIdx.x * 16 + w * 4;

    __shared__ __align__(16) unsigned short As[64 * LDA];

    for (int i = tid; i < 64 * K8; i += 256) {
        int r = i / K8, k8 = i - r * K8;
        *(bf16x8*)(&As[r * LDA + k8 * 8]) =
            *(const bf16x8*)(A + (size_t)(mbase + r) * K + k8 * 8);
    }

    const bf16x8* wb = (const bf16x8*)wf + (size_t)z * KSN * NT * 64;
    bf16x8 bf[4], bfn[4];
#pragma unroll
    for (int ntl = 0; ntl < 4; ++ntl) bf[ntl] = wb[(size_t)(0 * NT + ntb + ntl) * 64 + l];

    f32x4 acc[4][4];
#pragma unroll
    for (int ntl = 0; ntl < 4; ++ntl) {
        float bv = bias[(size_t)z * N + (ntb + ntl) * 16 + arow];
#pragma unroll
        for (int mt = 0; mt < 4; ++mt) acc[mt][ntl] = f32x4{bv, bv, bv, bv};
    }
    __syncthreads();

#pragma unroll
    for (int ks = 0; ks < KSN; ++ks) {
        if (ks < KSN - 1) {
#pragma unroll
            for (int ntl = 0; ntl < 4; ++ntl)
                bfn[ntl] = wb[(size_t)((ks + 1) * NT + ntb + ntl) * 64 + l];
        }
        bf16x8 af[4];
#pragma unroll
        for (int mt = 0; mt < 4; ++mt)
            af[mt] = *(const bf16x8*)(&As[(mt * 16 + arow) * LDA + ks * 32 + kq * 8]);
#pragma unroll
        for (int mt = 0; mt < 4; ++mt)
#pragma unroll
            for (int ntl = 0; ntl < 4; ++ntl)
                acc[mt][ntl] = __builtin_amdgcn_mfma_f32_16x16x32_bf16(af[mt], bf[ntl], acc[mt][ntl], 0, 0, 0);
#pragma unroll
        for (int ntl = 0; ntl < 4; ++ntl) bf[ntl] = bfn[ntl];
    }

    if constexpr (TO_XGF) {
        // fused reorder: xgf float index = d*2097152 +
        //   (t*4096 + (j>>4)*256 + ((j>>2)&3)*64 + (j&3)*16 + b)*4 + q,
        // n = q*256 + j, m = b*128 + t; value scaled x64.
        float* base = out + (size_t)z * 2097152;
#pragma unroll
        for (int mt = 0; mt < 4; ++mt)
#pragma unroll
            for (int ntl = 0; ntl < 4; ++ntl) {
                int ncol = (ntb + ntl) * 16 + arow;
                int q = ncol >> 8;
                int j = ncol & 255;
                int jpart = (j >> 4) * 256 + ((j >> 2) & 3) * 64 + (j & 3) * 16;
#pragma unroll
                for (int reg = 0; reg < 4; ++reg) {
                    int m = mbase + mt * 16 + kq * 4 + reg;
                    int b = m >> 7, t = m & 127;
                    base[(size_t)(t * 4096 + jpart + b) * 4 + q] = acc[mt][ntl][reg] * 64.f;
                }
            }
    } else {
        float* oz = out + (size_t)z * 2048 * N;
#pragma unroll
        for (int mt = 0; mt < 4; ++mt)
#pragma unroll
            for (int ntl = 0; ntl < 4; ++ntl) {
                int ncol = (ntb + ntl) * 16 + arow;
#pragma unroll
                for (int reg = 0; reg < 4; ++reg) {
                    int m = mbase + mt * 16 + kq * 4 + reg;
                    oz[(size_t)m * N + ncol] = acc[mt][ntl][reg];
                }
            }
    }
}

// ---------------- MFMA LSTM recurrence (R11 exact, measured-best 252us) ----
#define GATE8(A, C, H) { \
    float gi = A[0] * 0.015625f, gf = A[1] * 0.015625f, gg = A[2] * 0.015625f, go = A[3] * 0.015625f; \
    float si = __builtin_amdgcn_rcpf(1.f + __expf(-gi)); \
    float sf = __builtin_amdgcn_rcpf(1.f + __expf(-gf)); \
    float so = __builtin_amdgcn_rcpf(1.f + __expf(-go)); \
    float eg = __expf(2.f * gg); \
    float tg = 1.f - 2.f * __builtin_amdgcn_rcpf(eg + 1.f); \
    C = sf * C + si * tg; \
    float ec = __expf(2.f * C); \
    float tc = 1.f - 2.f * __builtin_amdgcn_rcpf(ec + 1.f); \
    H = so * tc; }

__global__ __launch_bounds__(512, 2) void k_lstm_mfma(
    const float* __restrict__ xgf,            // [2][128][16][4][64][4], pre-scaled x64
    const unsigned char* __restrict__ Wfrag8, // [2][16][8][4][64][8] fp8 of 64*Whh (k-perm)
    unsigned short* __restrict__ embt)        // [128][512][16] bf16 ([t][j][b])
{
    const int d = blockIdx.x;
    const int tid = threadIdx.x;
    const int wv = tid >> 6;      // 0..7
    const int l = tid & 63;
    const int b = l & 15;
    const int jh = l >> 4;
    const int s0 = wv * 2, s1 = wv * 2 + 1;

    __shared__ __align__(8) unsigned char hB[4096];   // fp8 h, single buffer

    const unsigned char* wg0 = Wfrag8 + ((size_t)(d * 16 + s0)) * 16384;
    const unsigned char* wg1 = Wfrag8 + ((size_t)(d * 16 + s1)) * 16384;
    long W0[8][4], W1[8][4];
#pragma unroll
    for (int ks = 0; ks < 8; ++ks)
#pragma unroll
        for (int t4 = 0; t4 < 4; ++t4) {
            W0[ks][t4] = *(const long*)(wg0 + ((size_t)((ks * 4 + t4) * 64 + l)) * 8);
            W1[ks][t4] = *(const long*)(wg1 + ((size_t)((ks * 4 + t4) * 64 + l)) * 8);
        }
#pragma unroll
    for (int ks = 0; ks < 8; ++ks)
#pragma unroll
        for (int t4 = 0; t4 < 4; ++t4) {
            asm volatile("" : "+v"(W0[ks][t4]));
            asm volatile("" : "+v"(W1[ks][t4]));
        }

    ((uint64_t*)hB)[tid] = 0ull;

    const int sgn = d ? -1 : 1;
    int t = d ? 127 : 0;
    const f32x4* xb = (const f32x4*)(xgf) + (size_t)d * 524288;
    const int xo0 = s0 * 256 + l;
    const int xo1 = s1 * 256 + l;

    f32x4 a0 = xb[t * 4096 + xo0];
    f32x4 a1 = xb[t * 4096 + xo0 + 64];
    f32x4 a2 = xb[t * 4096 + xo0 + 128];
    f32x4 a3 = xb[t * 4096 + xo0 + 192];
    f32x4 e0 = xb[t * 4096 + xo1];
    f32x4 e1 = xb[t * 4096 + xo1 + 64];
    f32x4 e2 = xb[t * 4096 + xo1 + 128];
    f32x4 e3 = xb[t * 4096 + xo1 + 192];

    float c0 = 0.f, c1 = 0.f, c2 = 0.f, c3 = 0.f;
    float c4 = 0.f, c5 = 0.f, c6 = 0.f, c7 = 0.f;
    const int hrd = jh * 128 + b * 8;
    unsigned short* ep0 = embt + (size_t)d * 4096 + (size_t)s0 * 256 + l;
    unsigned short* ep1 = embt + (size_t)d * 4096 + (size_t)s1 * 256 + l;
    unsigned char* hw0 = hB + s0 * 256 + b * 8 + jh * 2;
    unsigned char* hw1 = hB + s1 * 256 + b * 8 + jh * 2;
    __syncthreads();

    for (int s = 0; s < 128; ++s) {
#pragma unroll
        for (int ks = 0; ks < 8; ++ks) {
            long hf = *(const long*)(hB + ks * 512 + hrd);
            a0 = __builtin_amdgcn_mfma_f32_16x16x32_fp8_fp8(W0[ks][0], hf, a0, 0, 0, 0);
            a1 = __builtin_amdgcn_mfma_f32_16x16x32_fp8_fp8(W0[ks][1], hf, a1, 0, 0, 0);
            a2 = __builtin_amdgcn_mfma_f32_16x16x32_fp8_fp8(W0[ks][2], hf, a2, 0, 0, 0);
            a3 = __builtin_amdgcn_mfma_f32_16x16x32_fp8_fp8(W0[ks][3], hf, a3, 0, 0, 0);
            e0 = __builtin_amdgcn_mfma_f32_16x16x32_fp8_fp8(W1[ks][0], hf, e0, 0, 0, 0);
            e1 = __builtin_amdgcn_mfma_f32_16x16x32_fp8_fp8(W1[ks][1], hf, e1, 0, 0, 0);
            e2 = __builtin_amdgcn_mfma_f32_16x16x32_fp8_fp8(W1[ks][2], hf, e2, 0, 0, 0);
            e3 = __builtin_amdgcn_mfma_f32_16x16x32_fp8_fp8(W1[ks][3], hf, e3, 0, 0, 0);
        }

        float h0, h1, h2, h3, h4, h5, h6, h7;
        GATE8(a0, c0, h0);
        GATE8(a1, c1, h1);
        GATE8(a2, c2, h2);
        GATE8(a3, c3, h3);
        GATE8(e0, c4, h4);
        GATE8(e1, c5, h5);
        GATE8(e2, c6, h6);
        GATE8(e3, c7, h7);

        unsigned r01, r23, r45, r67;
        asm("v_cvt_pk_bf16_f32 %0, %1, %2" : "=v"(r01) : "v"(h0), "v"(h1));
        asm("v_cvt_pk_bf16_f32 %0, %1, %2" : "=v"(r23) : "v"(h2), "v"(h3));
        asm("v_cvt_pk_bf16_f32 %0, %1, %2" : "=v"(r45) : "v"(h4), "v"(h5));
        asm("v_cvt_pk_bf16_f32 %0, %1, %2" : "=v"(r67) : "v"(h6), "v"(h7));
        {
            unsigned short* p0 = ep0 + (size_t)t * 8192;
            p0[0]   = (unsigned short)r01;
            p0[64]  = (unsigned short)(r01 >> 16);
            p0[128] = (unsigned short)r23;
            p0[192] = (unsigned short)(r23 >> 16);
            unsigned short* p1 = ep1 + (size_t)t * 8192;
            p1[0]   = (unsigned short)r45;
            p1[64]  = (unsigned short)(r45 >> 16);
            p1[128] = (unsigned short)r67;
            p1[192] = (unsigned short)(r67 >> 16);
        }

        unsigned q01 = __builtin_amdgcn_cvt_pk_fp8_f32(h0, h1, 0, false);
        unsigned q23 = __builtin_amdgcn_cvt_pk_fp8_f32(h2, h3, 0, false);
        unsigned q45 = __builtin_amdgcn_cvt_pk_fp8_f32(h4, h5, 0, false);
        unsigned q67 = __builtin_amdgcn_cvt_pk_fp8_f32(h6, h7, 0, false);

        int tn = (s == 127) ? t : (t + sgn);
        a0 = xb[tn * 4096 + xo0];
        a1 = xb[tn * 4096 + xo0 + 64];
        a2 = xb[tn * 4096 + xo0 + 128];
        a3 = xb[tn * 4096 + xo0 + 192];
        e0 = xb[tn * 4096 + xo1];
        e1 = xb[tn * 4096 + xo1 + 64];
        e2 = xb[tn * 4096 + xo1 + 128];
        e3 = xb[tn * 4096 + xo1 + 192];
        __syncthreads();
        *(unsigned short*)(hw0)       = (unsigned short)q01;
        *(unsigned short*)(hw0 + 128) = (unsigned short)q23;
        *(unsigned short*)(hw1)       = (unsigned short)q45;
        *(unsigned short*)(hw1 + 128) = (unsigned short)q67;
        __syncthreads();
        t = tn;
    }
}

// ---------------- MFMA pairwise scorer (R7 winner, unchanged) ----------------
__global__ __launch_bounds__(256, 2) void k_scorer_mfma(
    const float* __restrict__ HaHb, const unsigned short* __restrict__ w2f,
    const float* __restrict__ b2, const float* __restrict__ W3,
    const float* __restrict__ b3v, float* __restrict__ score)
{
    const int jt = blockIdx.x, it = blockIdx.y, b = blockIdx.z;
    const int j0 = jt * 16, i0 = it * 16;
    const int tid = threadIdx.x;
    const int w = tid >> 6;
    const int l = tid & 63;
    const int n_l = l & 15;
    const int kq = l >> 4;

    __shared__ __align__(16) unsigned short HaS[16 * 264];
    __shared__ __align__(16) unsigned short HbS[16 * 264];

    {
        const float* base = HaHb + ((size_t)(b * 128)) * 512;
        int rr = tid >> 4;
        int q = tid & 15;
#pragma unroll
        for (int rep = 0; rep < 4; ++rep) {
            int k0 = q * 4 + rep * 64;
            float4 va = *(const float4*)(base + (size_t)(i0 + rr) * 512 + k0);
            float4 vb = *(const float4*)(base + (size_t)(j0 + rr) * 512 + 256 + k0);
            u16x4 ua = { f2bf(va.x), f2bf(va.y), f2bf(va.z), f2bf(va.w) };
            u16x4 ub = { f2bf(vb.x), f2bf(vb.y), f2bf(vb.z), f2bf(vb.w) };
            *(u16x4*)(&HaS[rr * 264 + k0]) = ua;
            *(u16x4*)(&HbS[rr * 264 + k0]) = ub;
        }
    }

    float b2v[8], w3v[8];
#pragma unroll
    for (int nt = 0; nt < 8; ++nt) {
        b2v[nt] = b2[nt * 16 + n_l];
        w3v[nt] = W3[nt * 16 + n_l];
    }

    f32x4 acc[4][8];
#pragma unroll
    for (int il = 0; il < 4; ++il)
#pragma unroll
        for (int nt = 0; nt < 8; ++nt) acc[il][nt] = f32x4{0.f, 0.f, 0.f, 0.f};

    const bf16x8* wbase = (const bf16x8*)w2f;
    bf16x8 wf[8], wfn[8];
#pragma unroll
    for (int nt = 0; nt < 8; ++nt) wf[nt] = wbase[(nt * 8 + 0) * 64 + l];

    __syncthreads();

#pragma unroll
    for (int ks = 0; ks < 8; ++ks) {
        if (ks < 7) {
#pragma unroll
            for (int nt = 0; nt < 8; ++nt) wfn[nt] = wbase[(nt * 8 + ks + 1) * 64 + l];
        }
#pragma unroll
        for (int il = 0; il < 4; ++il) {
            const int irow = w * 4 + il;
            bf16x8 ha = *(const bf16x8*)(&HaS[irow * 264 + ks * 32 + kq * 8]);
            bf16x8 hb = *(const bf16x8*)(&HbS[n_l * 264 + ks * 32 + kq * 8]);
            bf16x8 av;
#pragma unroll
            for (int e = 0; e < 8; ++e) {
                float v = bf2f((unsigned short)ha[e]) + bf2f((unsigned short)hb[e]);
                v = v > 0.f ? v : 0.f;
                av[e] = (short)f2bf(v);
            }
#pragma unroll
            for (int nt = 0; nt < 8; ++nt)
                acc[il][nt] = __builtin_amdgcn_mfma_f32_16x16x32_bf16(av, wf[nt], acc[il][nt], 0, 0, 0);
        }
#pragma unroll
        for (int nt = 0; nt < 8; ++nt) wf[nt] = wfn[nt];
    }

    const float bb3 = b3v[0];
#pragma unroll
    for (int il = 0; il < 4; ++il) {
        float p[4];
#pragma unroll
        for (int reg = 0; reg < 4; ++reg) {
            float v = 0.f;
#pragma unroll
            for (int nt = 0; nt < 8; ++nt) {
                float h2v = acc[il][nt][reg] + b2v[nt];
                h2v = h2v > 0.f ? h2v : 0.f;
                v += h2v * w3v[nt];
            }
            p[reg] = v;
        }
#pragma unroll
        for (int m = 1; m < 16; m <<= 1) {
            p[0] += __shfl_xor(p[0], m);
            p[1] += __shfl_xor(p[1], m);
            p[2] += __shfl_xor(p[2], m);
            p[3] += __shfl_xor(p[3], m);
        }
        if (n_l == 0) {
            const int i = i0 + w * 4 + il;
            const int jb = j0 + kq * 4;
            float4 sv;
            float* pv = &sv.x;
#pragma unroll
            for (int reg = 0; reg < 4; ++reg) {
                int jg = jb + reg;
                float sc = p[reg] + bb3;
                sc = sc > 0.f ? sc : 0.f;
                if (jg == i || jg == 0) sc = 0.f;
                pv[reg] = sc;
            }
            *(float4*)(&score[((size_t)(b * 128 + i)) * 128 + jb]) = sv;
        }
    }
}

// ---------------- loss ----------------
__global__ __launch_bounds__(128) void k_loss1(
    const float* __restrict__ score, const int* __restrict__ tree, float* __restrict__ res)
{
    int k = blockIdx.x;
    int b = blockIdx.y;
    int head = tree[((size_t)b * 128 + k + 1) * 2 + 0];
    int dep  = tree[((size_t)b * 128 + k + 1) * 2 + 1];
    int i = threadIdx.x;
    float s = score[((size_t)b * 128 + i) * 128 + dep];
    float v = (i == dep) ? 0.f : __expf(s);
    __shared__ float redu[2];
#pragma unroll
    for (int off = 32; off >= 1; off >>= 1) v += __shfl_down(v, off, 64);
    if ((i & 63) == 0) redu[i >> 6] = v;
    __syncthreads();
    if (i == 0) {
        float norm = redu[0] + redu[1];
        float num = score[((size_t)b * 128 + head) * 128 + dep];
        res[b * 127 + k] = __logf(norm) - num;
    }
}

__global__ __launch_bounds__(256) void k_loss2(const float* __restrict__ res, float* __restrict__ out) {
    int tid = threadIdx.x;
    float a = 0.f;
    for (int idx = tid; idx < 16 * 127; idx += 256) a += res[idx];
    __shared__ float sm[256];
    sm[tid] = a;
    __syncthreads();
    for (int off = 128; off >= 1; off >>= 1) {
        if (tid < off) sm[tid] += sm[tid + off];
        __syncthreads();
    }
    if (tid == 0) out[0] = sm[0] / 127.f;
}

// ---------------- host launcher ----------------
extern "C" void kernel_launch(void* const* d_in, const int* in_sizes, int n_in,
                              void* d_out, int out_size, void* d_ws, size_t ws_size,
                              hipStream_t stream) {
    (void)in_sizes; (void)n_in; (void)out_size; (void)ws_size;
    const float* X    = (const float*)d_in[0];
    const float* Wih0 = (const float*)d_in[1];
    const float* Whh0 = (const float*)d_in[2];
    const float* bih0 = (const float*)d_in[3];
    const float* bhh0 = (const float*)d_in[4];
    const float* Wih1 = (const float*)d_in[5];
    const float* Whh1 = (const float*)d_in[6];
    const float* bih1 = (const float*)d_in[7];
    const float* bhh1 = (const float*)d_in[8];
    const float* W1   = (const float*)d_in[9];
    const float* b1   = (const float*)d_in[10];
    const float* W2   = (const float*)d_in[11];
    const float* b2   = (const float*)d_in[12];
    const float* W3   = (const float*)d_in[13];
    const float* b3   = (const float*)d_in[14];
    const int*   tree = (const int*)d_in[15];
    float* out = (float*)d_out;   // [0]=loss, [1..]=score

    float* ws = (float*)d_ws;
    size_t o = 0;
    float* bsum0 = ws + o; o += 2048;
    float* bsum1 = ws + o; o += 2048;
    float* bhab  = ws + o; o += 512;
    unsigned char* Wf0 = (unsigned char*)(ws + o); o += (size_t)2 * 16 * 16384 / 4;
    unsigned char* Wf1 = (unsigned char*)(ws + o); o += (size_t)2 * 16 * 16384 / 4;
    unsigned short* w2f   = (unsigned short*)(ws + o); o += (size_t)4096 * 8 / 2;
    unsigned short* wfIh0 = (unsigned short*)(ws + o); o += (size_t)2 * 7 * 64 * 64 * 8 / 2;
    unsigned short* wfIh1 = (unsigned short*)(ws + o); o += (size_t)2 * 16 * 64 * 64 * 8 / 2;
    unsigned short* wfW1  = (unsigned short*)(ws + o); o += (size_t)16 * 32 * 64 * 8 / 2;
    unsigned short* Xb    = (unsigned short*)(ws + o); o += (size_t)2048 * 224 / 2;
    float* xgf  = ws + o; o += (size_t)2 * 2048 * 1024;
    unsigned short* embt0 = (unsigned short*)(ws + o); o += (size_t)128 * 512 * 16 / 2;
    unsigned short* embt1 = (unsigned short*)(ws + o); o += (size_t)128 * 512 * 16 / 2;
    unsigned short* embR  = (unsigned short*)(ws + o); o += (size_t)2048 * 512 / 2;
    float* HaHb = ws + o; o += (size_t)2048 * 512;
    float* res  = ws + o; o += 2048;

    // prep
    k_wfrag8<<<256, 256, 0, stream>>>(Whh0, Wf0);
    k_wfrag8<<<256, 256, 0, stream>>>(Whh1, Wf1);
    k_w2frag<<<16, 256, 0, stream>>>(W2, w2f);
    k_wfragb<<<224, 256, 0, stream>>>(Wih0, wfIh0, 7, 64, 200, 2 * 7 * 64 * 64);
    k_wfragb<<<512, 256, 0, stream>>>(Wih1, wfIh1, 16, 64, 512, 2 * 16 * 64 * 64);
    k_wfragb_w1<<<128, 256, 0, stream>>>(W1, wfW1);
    k_xbf16<<<1792, 256, 0, stream>>>(X, Xb);
    k_bias<<<18, 256, 0, stream>>>(bih0, bhh0, bih1, bhh1, b1, bsum0, bsum1, bhab);

    // layer 0 (MFMA GEMM, K=224 zero-padded, fused reorder -> xgf)
    k_mgemm<224, true><<<dim3(4, 32, 2), 256, 0, stream>>>(Xb, wfIh0, bsum0, xgf, 1024);
    k_lstm_mfma<<<2, 512, 0, stream>>>(xgf, Wf0, embt0);
    // layer 1 (MFMA GEMM, K=512, fused reorder -> xgf)
    k_embR<<<128, 256, 0, stream>>>(embt0, embR);
    k_mgemm<512, true><<<dim3(4, 32, 2), 256, 0, stream>>>(embR, wfIh1, bsum1, xgf, 1024);
    k_lstm_mfma<<<2, 512, 0, stream>>>(xgf, Wf1, embt1);
    // Ha|Hb (MFMA GEMM, K=512, plain output)
    k_embR<<<128, 256, 0, stream>>>(embt1, embR);
    k_mgemm<512, false><<<dim3(2, 32, 1), 256, 0, stream>>>(embR, wfW1, bhab, HaHb, 512);
    // scorer -> out+1
    k_scorer_mfma<<<dim3(8, 8, 16), 256, 0, stream>>>(HaHb, w2f, b2, W3, b3, out + 1);
    // loss
    k_loss1<<<dim3(127, 16), 128, 0, stream>>>(out + 1, tree, res);
    k_loss2<<<1, 256, 0, stream>>>(res, out);
}